// Round 2
// baseline (1483.117 us; speedup 1.0000x reference)
//
#include <hip/hip_runtime.h>
#include <math.h>

#pragma clang fp contract(off)

#define A_TOTAL 196416
#define BATCH 8
#define KTOT 4576
#define NLEV 5
#define MASK_STRIDE 16   // 16 u64 words = 1024 bits per row
#define SPLIT 8          // row-split blocks per (batch,level) in k_mask

static __device__ const int d_aoff[NLEV] = {0, 147456, 184320, 193536, 195840};
static __device__ const int d_n[NLEV]    = {147456, 36864, 9216, 2304, 576};
static __device__ const int d_k[NLEV]    = {1000, 1000, 1000, 1000, 576};
static __device__ const int d_koff[NLEV] = {0, 1000, 2000, 3000, 4000};

// monotone map: f32 -> u32 preserving order (no NaNs in this data)
__device__ inline unsigned int mono(float f) {
  unsigned int u = __float_as_uint(f);
  return (u & 0x80000000u) ? ~u : (u | 0x80000000u);
}

// in-LDS bitonic ascending sort; all threads of the block must call
template <typename T>
__device__ inline void bitonic_sort(T* arr, int N, int tid, int nth) {
  for (int size = 2; size <= N; size <<= 1) {
    for (int stride = size >> 1; stride > 0; stride >>= 1) {
      __syncthreads();
      for (int e = tid; e < N; e += nth) {
        int partner = e ^ stride;
        if (partner > e) {
          T a = arr[e], b2 = arr[partner];
          bool up = ((e & size) == 0);
          if (up ? (a > b2) : (a < b2)) { arr[e] = b2; arr[partner] = a; }
        }
      }
    }
  }
  __syncthreads();
}

// ---------------------------------------------------------------------------
// K1: per (batch, level) exact top-k (lax.top_k semantics: value desc, idx asc)
// ---------------------------------------------------------------------------
__global__ __launch_bounds__(1024) void k_topk(const float* __restrict__ obj,
                                               int* __restrict__ sel_idx,
                                               float* __restrict__ maxv) {
  int bx = blockIdx.x;
  int b = bx / NLEV, l = bx % NLEV;
  int tid = threadIdx.x;
  if (tid == 0 && bx < BATCH) maxv[bx] = 0.0f;  // init for K2's atomicMax (coords >= 0)
  const int aoff = d_aoff[l], n = d_n[l], k = d_k[l], koff = d_koff[l];
  const float* ob = obj + (size_t)b * A_TOTAL + aoff;

  __shared__ int hist[256];
  __shared__ unsigned int s_prefix;
  __shared__ int s_need, s_cntgt, s_cnteq;
  __shared__ unsigned long long cand[1024];
  __shared__ unsigned int ties[2048];

  if (tid == 0) { s_prefix = 0u; s_need = k; }
  __syncthreads();

  for (int p = 3; p >= 0; --p) {
    if (tid < 256) hist[tid] = 0;
    __syncthreads();
    unsigned int mask_hi = (p == 3) ? 0u : (0xFFFFFFFFu << (8 * (p + 1)));
    unsigned int pref = s_prefix;
    for (int i = tid; i < n; i += 1024) {
      unsigned int key = mono(ob[i]);
      if ((key & mask_hi) == pref)
        atomicAdd(&hist[(key >> (8 * p)) & 255], 1);
    }
    __syncthreads();
    if (tid == 0) {
      int cum = 0, need = s_need, d;
      for (d = 255; d >= 0; --d) {
        int c = hist[d];
        if (cum + c >= need) { s_need = need - cum; break; }
        cum += c;
      }
      s_prefix = pref | ((unsigned int)d << (8 * p));
    }
    __syncthreads();
  }
  unsigned int T = s_prefix;  // exact key of the k-th largest
  int r = s_need;             // how many ties at T to take (smallest indices)

  if (tid == 0) { s_cntgt = 0; s_cnteq = 0; }
  __syncthreads();
  for (int i = tid; i < n; i += 1024) {
    unsigned int key = mono(ob[i]);
    if (key > T) {
      int slot = atomicAdd(&s_cntgt, 1);
      if (slot < 1024)
        cand[slot] = ((unsigned long long)key << 32) | (unsigned int)(~(unsigned int)i);
    } else if (key == T) {
      int slot = atomicAdd(&s_cnteq, 1);
      if (slot < 2048) ties[slot] = (unsigned int)i;
    }
  }
  __syncthreads();
  int cgt = min(s_cntgt, 1024);   // == k - r by construction
  int ne = min(s_cnteq, 2048);
  for (int i = tid; i < 2048; i += 1024) if (i >= ne) ties[i] = 0xFFFFFFFFu;
  __syncthreads();
  bitonic_sort(ties, 2048, tid, 1024);   // ascending index
  if (tid < r && cgt + tid < 1024)
    cand[cgt + tid] = ((unsigned long long)T << 32) | (unsigned int)(~ties[tid]);
  for (int i = tid; i < 1024; i += 1024) if (i >= cgt + r) cand[i] = 0ull;
  __syncthreads();
  bitonic_sort(cand, 1024, tid, 1024);   // ascending composite
  if (tid < k) {
    unsigned long long e = cand[1023 - tid];               // rank tid (desc value, asc idx)
    unsigned int idx = ~(unsigned int)(e & 0xFFFFFFFFull);
    sel_idx[b * KTOT + koff + tid] = aoff + (int)idx;
  }
}

// ---------------------------------------------------------------------------
// K2: decode + clip + sigmoid + validity for the selected 8x4576 anchors
// ---------------------------------------------------------------------------
__global__ void k_decode(const float* __restrict__ obj,
                         const float* __restrict__ deltas,
                         const float* __restrict__ anchors,
                         const int* __restrict__ sel_idx,
                         float* __restrict__ boxes,
                         float* __restrict__ sprime,
                         float* __restrict__ maxv) {
  int g = blockIdx.x * blockDim.x + threadIdx.x;
  if (g >= BATCH * KTOT) return;
  int b = g / KTOT;
  int gidx = sel_idx[g];
  float o = obj[(size_t)b * A_TOTAL + gidx];
  const float* dl = deltas + ((size_t)b * A_TOTAL + gidx) * 4;
  const float* an = anchors + (size_t)gidx * 4;
  float a0 = an[0], a1 = an[1], a2 = an[2], a3 = an[3];
  float wa = a2 - a0, ha = a3 - a1;
  float cxa = a0 + 0.5f * wa, cya = a1 + 0.5f * ha;
  float dx = dl[0], dy = dl[1];
  const float CLIPV = 4.135166556742356f;  // log(1000/16)
  float dw = fminf(dl[2], CLIPV), dh = fminf(dl[3], CLIPV);
  float pcx = dx * wa + cxa;               // contract(off): separate mul+add like numpy
  float pcy = dy * ha + cya;
  float pw = (float)exp((double)dw) * wa;  // correctly-rounded f32 exp
  float ph = (float)exp((double)dh) * ha;
  float x1 = pcx - 0.5f * pw, y1 = pcy - 0.5f * ph;
  float x2 = pcx + 0.5f * pw, y2 = pcy + 0.5f * ph;
  x1 = fminf(fmaxf(x1, 0.0f), 1024.0f);
  x2 = fminf(fmaxf(x2, 0.0f), 1024.0f);
  y1 = fminf(fmaxf(y1, 0.0f), 768.0f);
  y2 = fminf(fmaxf(y2, 0.0f), 768.0f);
  boxes[(size_t)g * 4 + 0] = x1;
  boxes[(size_t)g * 4 + 1] = y1;
  boxes[(size_t)g * 4 + 2] = x2;
  boxes[(size_t)g * 4 + 3] = y2;
  float s = (float)(1.0 / (1.0 + exp(-(double)o)));  // correctly-rounded sigmoid
  bool valid = ((x2 - x1) >= 1.0f) && ((y2 - y1) >= 1.0f) && (s >= 0.0f);
  sprime[g] = valid ? s : -1.0f;
  float mx = fmaxf(fmaxf(x1, y1), fmaxf(x2, y2));
  atomicMax((unsigned int*)&maxv[b], __float_as_uint(mx));  // coords >= 0 -> uint order ok
}

// ---------------------------------------------------------------------------
// K3: per-image stable sort of 4576 entries by (s' desc, pos asc); gather
// ---------------------------------------------------------------------------
__global__ __launch_bounds__(1024) void k_sort(const float* __restrict__ sprime,
                                               const float* __restrict__ boxes,
                                               float* __restrict__ score_sorted,
                                               float* __restrict__ boxes_sorted,
                                               int* __restrict__ lvl_sorted) {
  int b = blockIdx.x, tid = threadIdx.x;
  __shared__ unsigned long long skey[8192];  // 64 KB
  for (int e = tid; e < 8192; e += 1024) {
    if (e < KTOT) {
      unsigned int m = mono(sprime[b * KTOT + e]);
      skey[e] = ((unsigned long long)m << 32) | (unsigned int)(8191 - e);  // tie: smaller pos wins
    } else {
      skey[e] = 0ull;  // below mono(-1.0)
    }
  }
  __syncthreads();
  bitonic_sort(skey, 8192, tid, 1024);
  for (int j = tid; j < KTOT; j += 1024) {
    unsigned long long e = skey[8191 - j];  // rank j in descending order
    int p = 8191 - (int)(e & 0xFFFFFFFFull);
    score_sorted[b * KTOT + j] = sprime[b * KTOT + p];
    int lv = (p < 1000) ? 0 : (p < 2000) ? 1 : (p < 3000) ? 2 : (p < 4000) ? 3 : 4;
    lvl_sorted[b * KTOT + j] = lv;
    for (int c = 0; c < 4; ++c)
      boxes_sorted[((size_t)(b * KTOT + j)) * 4 + c] = boxes[((size_t)(b * KTOT + p)) * 4 + c];
  }
}

// ---------------------------------------------------------------------------
// K4a: per-(batch,level) IoU bitmask matrix (torchvision-GPU NMS, phase 1).
// Cross-level IoU is exactly 0 (offset gap >= 1) -> levels independent.
// Each of SPLIT blocks per (b,l) redoes the cheap LDS compaction, then
// computes 1024-bit suppression rows for its row range. part==0 also emits
// pos_lvl (level rank -> global sorted index) and the validity bitmask.
// ---------------------------------------------------------------------------
__global__ __launch_bounds__(256) void k_mask(const float* __restrict__ boxes_sorted,
                                              const float* __restrict__ score_sorted,
                                              const int* __restrict__ lvl_sorted,
                                              const float* __restrict__ maxv,
                                              unsigned long long* __restrict__ masks,
                                              int* __restrict__ pos_lvl,
                                              unsigned long long* __restrict__ validmask) {
  int blk = blockIdx.x;
  int bl = blk / SPLIT, part = blk % SPLIT;
  int b = bl / NLEV, l = bl % NLEV;
  int tid = threadIdx.x;
  const int m = d_k[l];
  __shared__ float lx1[1024], ly1[1024], lx2[1024], ly2[1024], lar[1024];
  __shared__ int lval[1024], lpos[1024];
  __shared__ int s_wcnt[4], s_base;
  float off = (float)l * (maxv[b] + 1.0f);
  if (tid == 0) s_base = 0;
  __syncthreads();
  // ordered compaction of this level's entries (in sorted order) into LDS
  for (int chunk = 0; chunk < KTOT; chunk += 256) {
    int j = chunk + tid;
    bool match = (j < KTOT) && (lvl_sorted[b * KTOT + j] == l);
    unsigned long long mb = __ballot(match);
    if ((tid & 63) == 0) s_wcnt[tid >> 6] = __popcll(mb);
    __syncthreads();
    int rank = s_base + __popcll(mb & ((1ull << (tid & 63)) - 1ull));
    for (int w = 0; w < (tid >> 6); ++w) rank += s_wcnt[w];
    if (match) {
      const float* bp = boxes_sorted + ((size_t)(b * KTOT + j)) * 4;
      float x1 = bp[0] + off, y1 = bp[1] + off, x2 = bp[2] + off, y2 = bp[3] + off;
      lx1[rank] = x1; ly1[rank] = y1; lx2[rank] = x2; ly2[rank] = y2;
      lar[rank] = (x2 - x1) * (y2 - y1);
      lval[rank] = (score_sorted[b * KTOT + j] >= 0.0f) ? 1 : 0;
      lpos[rank] = j;
    }
    __syncthreads();
    if (tid == 0) s_base += s_wcnt[0] + s_wcnt[1] + s_wcnt[2] + s_wcnt[3];
    __syncthreads();
  }
  // row range for this part
  int rpp = (m + SPLIT - 1) / SPLIT;
  int row0 = part * rpp;
  int rows = min(rpp, m - row0);
  if (rows < 0) rows = 0;
  unsigned long long* M = masks + (size_t)bl * 1024 * MASK_STRIDE;
  for (int t = tid; t < rows * MASK_STRIDE; t += 256) {
    int i = row0 + t / MASK_STRIDE;
    int w = t % MASK_STRIDE;
    int jbase = w * 64;
    unsigned long long bits = 0ull;
    if (jbase + 63 > i && jbase < m) {  // only j>i, j<m matter
      float bx1 = lx1[i], by1 = ly1[i], bx2 = lx2[i], by2 = ly2[i], ba = lar[i];
      int jlo = max(jbase, i + 1), jhi = min(jbase + 64, m);
      for (int j = jlo; j < jhi; ++j) {
        float xx1 = fmaxf(bx1, lx1[j]), yy1 = fmaxf(by1, ly1[j]);
        float xx2 = fminf(bx2, lx2[j]), yy2 = fminf(by2, ly2[j]);
        float wd = fmaxf(xx2 - xx1, 0.0f), ht = fmaxf(yy2 - yy1, 0.0f);
        float inter = wd * ht;
        float denom = fmaxf(ba + lar[j] - inter, 1e-9f);
        if (inter / denom > 0.7f) bits |= (1ull << (j - jbase));
      }
    }
    M[(size_t)i * MASK_STRIDE + w] = bits;
  }
  if (part == 0) {
    for (int i = tid; i < m; i += 256) pos_lvl[bl * 1024 + i] = lpos[i];
    if (tid < MASK_STRIDE) {
      unsigned long long vm = 0ull;
      for (int j = 0; j < 64; ++j) {
        int i = tid * 64 + j;
        if (i < m && lval[i]) vm |= (1ull << j);
      }
      validmask[bl * MASK_STRIDE + tid] = vm;
    }
  }
}

// ---------------------------------------------------------------------------
// K4b: serial bitmask scan, one wave per (batch,level). Lane w (<16) owns
// suppression word w in a register; decision broadcast via __shfl; mask rows
// prefetched 8 ahead (loads are decision-independent).
// ---------------------------------------------------------------------------
__global__ __launch_bounds__(64) void k_scan(const unsigned long long* __restrict__ masks,
                                             const int* __restrict__ pos_lvl,
                                             const unsigned long long* __restrict__ validmask,
                                             int* __restrict__ keep_g) {
  int bl = blockIdx.x;
  int b = bl / NLEV, l = bl % NLEV;
  int lane = threadIdx.x;
  const int m = d_k[l];  // 1000 or 576 — both divisible by 8
  const unsigned long long* M = masks + (size_t)bl * 1024 * MASK_STRIDE;
  __shared__ unsigned char keep_lds[1024];
  unsigned long long remv = 0ull;
  if (lane < MASK_STRIDE) remv = ~validmask[bl * MASK_STRIDE + lane];  // invalid = pre-suppressed
  unsigned long long buf[8];
  bool owner = (lane < MASK_STRIDE);
  if (owner) {
#pragma unroll
    for (int u = 0; u < 8; ++u) buf[u] = M[(size_t)u * MASK_STRIDE + lane];
  }
  int nch = m / 8;
  for (int c = 0; c < nch; ++c) {
#pragma unroll
    for (int u = 0; u < 8; ++u) {
      int i = c * 8 + u;
      unsigned long long dw = __shfl(remv, i >> 6);
      int keep = (int)(((dw >> (i & 63)) & 1ull) ^ 1ull);
      if (owner) {
        if (keep) remv |= buf[u];
        int pi = i + 8;
        if (pi < m) buf[u] = M[(size_t)pi * MASK_STRIDE + lane];
      }
      if (lane == 0) keep_lds[i] = (unsigned char)keep;
    }
  }
  __syncthreads();
  for (int i = lane; i < m; i += 64)
    keep_g[b * KTOT + pos_lvl[bl * 1024 + i]] = keep_lds[i];
}

// ---------------------------------------------------------------------------
// K5: emit first 1000 kept (in global sorted order) per image; zero-pad rest
// ---------------------------------------------------------------------------
__global__ __launch_bounds__(256) void k_out(const float* __restrict__ boxes_sorted,
                                             const float* __restrict__ score_sorted,
                                             const int* __restrict__ keep_g,
                                             float* __restrict__ out) {
  int b = blockIdx.x, tid = threadIdx.x;
  __shared__ int s_wcnt[4], s_base;
  for (int i = tid; i < 5000; i += 256) out[(size_t)b * 5000 + i] = 0.0f;
  if (tid == 0) s_base = 0;
  __syncthreads();
  for (int chunk = 0; chunk < KTOT; chunk += 256) {
    int j = chunk + tid;
    bool match = (j < KTOT) && (keep_g[b * KTOT + j] != 0);
    unsigned long long mb = __ballot(match);
    if ((tid & 63) == 0) s_wcnt[tid >> 6] = __popcll(mb);
    __syncthreads();
    int rank = s_base + __popcll(mb & ((1ull << (tid & 63)) - 1ull));
    for (int w = 0; w < (tid >> 6); ++w) rank += s_wcnt[w];
    if (match && rank < 1000) {
      const float* bp = boxes_sorted + ((size_t)(b * KTOT + j)) * 4;
      float* op = out + ((size_t)(b * 1000 + rank)) * 5;
      op[0] = bp[0]; op[1] = bp[1]; op[2] = bp[2]; op[3] = bp[3];
      op[4] = score_sorted[b * KTOT + j];
    }
    __syncthreads();
    if (tid == 0) s_base += s_wcnt[0] + s_wcnt[1] + s_wcnt[2] + s_wcnt[3];
    __syncthreads();
  }
}

extern "C" void kernel_launch(void* const* d_in, const int* in_sizes, int n_in,
                              void* d_out, int out_size, void* d_ws, size_t ws_size,
                              hipStream_t stream) {
  const float* obj     = (const float*)d_in[0];
  const float* deltas  = (const float*)d_in[1];
  const float* anchors = (const float*)d_in[2];
  float* out = (float*)d_out;

  // workspace layout (~7.3 MB)
  int*   sel_idx      = (int*)d_ws;                          // [8*4576]
  float* boxes        = (float*)(sel_idx + BATCH * KTOT);    // [8*4576*4]
  float* sprime       = boxes + (size_t)BATCH * KTOT * 4;    // [8*4576]
  float* maxv         = sprime + BATCH * KTOT;               // [8]
  float* score_sorted = maxv + BATCH;                        // [8*4576]
  float* boxes_sorted = score_sorted + BATCH * KTOT;         // [8*4576*4]
  int*   lvl_sorted   = (int*)(boxes_sorted + (size_t)BATCH * KTOT * 4);  // [8*4576]
  int*   keep_g       = lvl_sorted + BATCH * KTOT;           // [8*4576]
  int*   pos_lvl      = keep_g + BATCH * KTOT;               // [40*1024]
  unsigned long long* validmask = (unsigned long long*)(((uintptr_t)(pos_lvl + BATCH * NLEV * 1024) + 15) & ~(uintptr_t)15);  // [40*16]
  unsigned long long* masks = validmask + BATCH * NLEV * MASK_STRIDE;      // [40*1024*16] = 5.24 MB

  hipLaunchKernelGGL(k_topk, dim3(BATCH * NLEV), dim3(1024), 0, stream, obj, sel_idx, maxv);
  hipLaunchKernelGGL(k_decode, dim3((BATCH * KTOT + 255) / 256), dim3(256), 0, stream,
                     obj, deltas, anchors, sel_idx, boxes, sprime, maxv);
  hipLaunchKernelGGL(k_sort, dim3(BATCH), dim3(1024), 0, stream,
                     sprime, boxes, score_sorted, boxes_sorted, lvl_sorted);
  hipLaunchKernelGGL(k_mask, dim3(BATCH * NLEV * SPLIT), dim3(256), 0, stream,
                     boxes_sorted, score_sorted, lvl_sorted, maxv, masks, pos_lvl, validmask);
  hipLaunchKernelGGL(k_scan, dim3(BATCH * NLEV), dim3(64), 0, stream,
                     masks, pos_lvl, validmask, keep_g);
  hipLaunchKernelGGL(k_out, dim3(BATCH), dim3(256), 0, stream,
                     boxes_sorted, score_sorted, keep_g, out);
}

// Round 3
// 974.331 us; speedup vs baseline: 1.5222x; 1.5222x over previous
//
#include <hip/hip_runtime.h>
#include <math.h>

#pragma clang fp contract(off)

#define A_TOTAL 196416
#define BATCH 8
#define KTOT 4576
#define NLEV 5
#define MASK_STRIDE 16   // 16 u64 words = 1024 bits per row
#define SPLIT 8          // row-split blocks per (batch,level) in k_mask
#define TB_CAP 4096      // top-k candidate buffer (worst observed need ~1.4k)

static __device__ const int d_aoff[NLEV] = {0, 147456, 184320, 193536, 195840};
static __device__ const int d_n[NLEV]    = {147456, 36864, 9216, 2304, 576};
static __device__ const int d_k[NLEV]    = {1000, 1000, 1000, 1000, 576};
static __device__ const int d_koff[NLEV] = {0, 1000, 2000, 3000, 4000};

// monotone map: f32 -> u32 preserving order (no NaNs in this data)
__device__ inline unsigned int mono(float f) {
  unsigned int u = __float_as_uint(f);
  return (u & 0x80000000u) ? ~u : (u | 0x80000000u);
}

// in-LDS bitonic ascending sort; all threads of the block must call
template <typename T>
__device__ inline void bitonic_sort(T* arr, int N, int tid, int nth) {
  for (int size = 2; size <= N; size <<= 1) {
    for (int stride = size >> 1; stride > 0; stride >>= 1) {
      __syncthreads();
      for (int e = tid; e < N; e += nth) {
        int partner = e ^ stride;
        if (partner > e) {
          T a = arr[e], b2 = arr[partner];
          bool up = ((e & size) == 0);
          if (up ? (a > b2) : (a < b2)) { arr[e] = b2; arr[partner] = a; }
        }
      }
    }
  }
  __syncthreads();
}

// ---------------------------------------------------------------------------
// K1: per (batch, level) exact top-k (lax.top_k semantics: value desc, idx asc)
// Pass A: 12-bit-prefix histogram (4096 bins kills the exponent-concentration
// same-address LDS-atomic serialization seen with 8-bit bins).
// Pass B: collect all (key, idx) with prefix >= P (cnt ~1.4k max) into LDS,
// one bitonic sort, emit first k. Two global scans total (was five).
// ---------------------------------------------------------------------------
__global__ __launch_bounds__(1024) void k_topk(const float* __restrict__ obj,
                                               int* __restrict__ sel_idx,
                                               float* __restrict__ maxv) {
  int bx = blockIdx.x;
  int b = bx / NLEV, l = bx % NLEV;
  int tid = threadIdx.x;
  if (tid == 0 && bx < BATCH) maxv[bx] = 0.0f;  // init for K2's atomicMax (coords >= 0)
  const int aoff = d_aoff[l], n = d_n[l], k = d_k[l], koff = d_koff[l];
  const float* ob = obj + (size_t)b * A_TOTAL + aoff;

  __shared__ int hist[4096];                    // 16 KB
  __shared__ unsigned long long buf[TB_CAP];    // 32 KB
  __shared__ int s_grp[256];
  __shared__ int s_cnt;
  __shared__ unsigned int s_P;

  for (int i = tid; i < 4096; i += 1024) hist[i] = 0;
  if (tid == 0) s_cnt = 0;
  __syncthreads();

  for (int i = tid; i < n; i += 1024) {
    unsigned int key = mono(ob[i]);
    atomicAdd(&hist[key >> 20], 1);
  }
  __syncthreads();
  // hierarchical threshold scan: 256 groups of 16 bins
  if (tid < 256) {
    int s = 0;
    for (int j = 0; j < 16; ++j) s += hist[tid * 16 + j];
    s_grp[tid] = s;
  }
  __syncthreads();
  if (tid == 0) {
    int cum = 0, g, d;
    for (g = 255; g >= 0; --g) {
      if (cum + s_grp[g] >= k) break;
      cum += s_grp[g];
    }
    for (d = 15; d >= 0; --d) {
      int c = hist[g * 16 + d];
      if (cum + c >= k) break;
      cum += c;
    }
    s_P = (unsigned int)(g * 16 + d);
  }
  __syncthreads();
  unsigned int P = s_P;  // count(prefix > P) < k <= count(prefix >= P)

  for (int i = tid; i < n; i += 1024) {
    unsigned int key = mono(ob[i]);
    if ((key >> 20) >= P) {
      int slot = atomicAdd(&s_cnt, 1);
      if (slot < TB_CAP)
        buf[slot] = ((unsigned long long)key << 32) | (unsigned int)(~(unsigned int)i);
    }
  }
  __syncthreads();
  int cnt = min(s_cnt, TB_CAP);
  for (int i = tid; i < TB_CAP; i += 1024) if (i >= cnt) buf[i] = 0ull;
  __syncthreads();
  bitonic_sort(buf, TB_CAP, tid, 1024);  // ascending (key asc, then idx desc)
  if (tid < k) {
    unsigned long long e = buf[TB_CAP - 1 - tid];  // rank tid: key desc, idx asc on ties
    unsigned int idx = ~(unsigned int)(e & 0xFFFFFFFFull);
    sel_idx[b * KTOT + koff + tid] = aoff + (int)idx;
  }
}

// ---------------------------------------------------------------------------
// K2: decode + clip + sigmoid + validity for the selected 8x4576 anchors.
// maxv via block-level LDS reduction -> <=2 global atomics per block
// (36608 same-address global atomics was a 412 us cross-XCD serialization).
// ---------------------------------------------------------------------------
__global__ __launch_bounds__(256) void k_decode(const float* __restrict__ obj,
                                                const float* __restrict__ deltas,
                                                const float* __restrict__ anchors,
                                                const int* __restrict__ sel_idx,
                                                float* __restrict__ boxes,
                                                float* __restrict__ sprime,
                                                float* __restrict__ maxv) {
  __shared__ unsigned int s_max[2];
  int g = blockIdx.x * 256 + threadIdx.x;
  int b0 = (blockIdx.x * 256) / KTOT;  // first batch this block touches
  if (threadIdx.x < 2) s_max[threadIdx.x] = 0u;
  __syncthreads();
  if (g < BATCH * KTOT) {
    int b = g / KTOT;
    int gidx = sel_idx[g];
    float o = obj[(size_t)b * A_TOTAL + gidx];
    const float* dl = deltas + ((size_t)b * A_TOTAL + gidx) * 4;
    const float* an = anchors + (size_t)gidx * 4;
    float a0 = an[0], a1 = an[1], a2 = an[2], a3 = an[3];
    float wa = a2 - a0, ha = a3 - a1;
    float cxa = a0 + 0.5f * wa, cya = a1 + 0.5f * ha;
    float dx = dl[0], dy = dl[1];
    const float CLIPV = 4.135166556742356f;  // log(1000/16)
    float dw = fminf(dl[2], CLIPV), dh = fminf(dl[3], CLIPV);
    float pcx = dx * wa + cxa;               // contract(off): separate mul+add like numpy
    float pcy = dy * ha + cya;
    float pw = (float)exp((double)dw) * wa;  // correctly-rounded f32 exp
    float ph = (float)exp((double)dh) * ha;
    float x1 = pcx - 0.5f * pw, y1 = pcy - 0.5f * ph;
    float x2 = pcx + 0.5f * pw, y2 = pcy + 0.5f * ph;
    x1 = fminf(fmaxf(x1, 0.0f), 1024.0f);
    x2 = fminf(fmaxf(x2, 0.0f), 1024.0f);
    y1 = fminf(fmaxf(y1, 0.0f), 768.0f);
    y2 = fminf(fmaxf(y2, 0.0f), 768.0f);
    boxes[(size_t)g * 4 + 0] = x1;
    boxes[(size_t)g * 4 + 1] = y1;
    boxes[(size_t)g * 4 + 2] = x2;
    boxes[(size_t)g * 4 + 3] = y2;
    float s = (float)(1.0 / (1.0 + exp(-(double)o)));  // correctly-rounded sigmoid
    bool valid = ((x2 - x1) >= 1.0f) && ((y2 - y1) >= 1.0f) && (s >= 0.0f);
    sprime[g] = valid ? s : -1.0f;
    float mx = fmaxf(fmaxf(x1, y1), fmaxf(x2, y2));
    atomicMax(&s_max[b - b0], __float_as_uint(mx));  // coords >= 0 -> uint order ok
  }
  __syncthreads();
  if (threadIdx.x < 2 && b0 + (int)threadIdx.x < BATCH)
    atomicMax((unsigned int*)&maxv[b0 + threadIdx.x], s_max[threadIdx.x]);
}

// ---------------------------------------------------------------------------
// K3: per-image stable sort of 4576 entries by (s' desc, pos asc); gather
// ---------------------------------------------------------------------------
__global__ __launch_bounds__(1024) void k_sort(const float* __restrict__ sprime,
                                               const float* __restrict__ boxes,
                                               float* __restrict__ score_sorted,
                                               float* __restrict__ boxes_sorted,
                                               int* __restrict__ lvl_sorted) {
  int b = blockIdx.x, tid = threadIdx.x;
  __shared__ unsigned long long skey[8192];  // 64 KB
  for (int e = tid; e < 8192; e += 1024) {
    if (e < KTOT) {
      unsigned int m = mono(sprime[b * KTOT + e]);
      skey[e] = ((unsigned long long)m << 32) | (unsigned int)(8191 - e);  // tie: smaller pos wins
    } else {
      skey[e] = 0ull;  // below mono(-1.0)
    }
  }
  __syncthreads();
  bitonic_sort(skey, 8192, tid, 1024);
  for (int j = tid; j < KTOT; j += 1024) {
    unsigned long long e = skey[8191 - j];  // rank j in descending order
    int p = 8191 - (int)(e & 0xFFFFFFFFull);
    score_sorted[b * KTOT + j] = sprime[b * KTOT + p];
    int lv = (p < 1000) ? 0 : (p < 2000) ? 1 : (p < 3000) ? 2 : (p < 4000) ? 3 : 4;
    lvl_sorted[b * KTOT + j] = lv;
    for (int c = 0; c < 4; ++c)
      boxes_sorted[((size_t)(b * KTOT + j)) * 4 + c] = boxes[((size_t)(b * KTOT + p)) * 4 + c];
  }
}

// ---------------------------------------------------------------------------
// K4a: per-(batch,level) IoU bitmask matrix (torchvision-GPU NMS, phase 1).
// ---------------------------------------------------------------------------
__global__ __launch_bounds__(256) void k_mask(const float* __restrict__ boxes_sorted,
                                              const float* __restrict__ score_sorted,
                                              const int* __restrict__ lvl_sorted,
                                              const float* __restrict__ maxv,
                                              unsigned long long* __restrict__ masks,
                                              int* __restrict__ pos_lvl,
                                              unsigned long long* __restrict__ validmask) {
  int blk = blockIdx.x;
  int bl = blk / SPLIT, part = blk % SPLIT;
  int b = bl / NLEV, l = bl % NLEV;
  int tid = threadIdx.x;
  const int m = d_k[l];
  __shared__ float lx1[1024], ly1[1024], lx2[1024], ly2[1024], lar[1024];
  __shared__ int lval[1024], lpos[1024];
  __shared__ int s_wcnt[4], s_base;
  float off = (float)l * (maxv[b] + 1.0f);
  if (tid == 0) s_base = 0;
  __syncthreads();
  // ordered compaction of this level's entries (in sorted order) into LDS
  for (int chunk = 0; chunk < KTOT; chunk += 256) {
    int j = chunk + tid;
    bool match = (j < KTOT) && (lvl_sorted[b * KTOT + j] == l);
    unsigned long long mb = __ballot(match);
    if ((tid & 63) == 0) s_wcnt[tid >> 6] = __popcll(mb);
    __syncthreads();
    int rank = s_base + __popcll(mb & ((1ull << (tid & 63)) - 1ull));
    for (int w = 0; w < (tid >> 6); ++w) rank += s_wcnt[w];
    if (match) {
      const float* bp = boxes_sorted + ((size_t)(b * KTOT + j)) * 4;
      float x1 = bp[0] + off, y1 = bp[1] + off, x2 = bp[2] + off, y2 = bp[3] + off;
      lx1[rank] = x1; ly1[rank] = y1; lx2[rank] = x2; ly2[rank] = y2;
      lar[rank] = (x2 - x1) * (y2 - y1);
      lval[rank] = (score_sorted[b * KTOT + j] >= 0.0f) ? 1 : 0;
      lpos[rank] = j;
    }
    __syncthreads();
    if (tid == 0) s_base += s_wcnt[0] + s_wcnt[1] + s_wcnt[2] + s_wcnt[3];
    __syncthreads();
  }
  // row range for this part
  int rpp = (m + SPLIT - 1) / SPLIT;
  int row0 = part * rpp;
  int rows = min(rpp, m - row0);
  if (rows < 0) rows = 0;
  unsigned long long* M = masks + (size_t)bl * 1024 * MASK_STRIDE;
  for (int t = tid; t < rows * MASK_STRIDE; t += 256) {
    int i = row0 + t / MASK_STRIDE;
    int w = t % MASK_STRIDE;
    int jbase = w * 64;
    unsigned long long bits = 0ull;
    if (jbase + 63 > i && jbase < m) {  // only j>i, j<m matter
      float bx1 = lx1[i], by1 = ly1[i], bx2 = lx2[i], by2 = ly2[i], ba = lar[i];
      int jlo = max(jbase, i + 1), jhi = min(jbase + 64, m);
      for (int j = jlo; j < jhi; ++j) {
        float xx1 = fmaxf(bx1, lx1[j]), yy1 = fmaxf(by1, ly1[j]);
        float xx2 = fminf(bx2, lx2[j]), yy2 = fminf(by2, ly2[j]);
        float wd = fmaxf(xx2 - xx1, 0.0f), ht = fmaxf(yy2 - yy1, 0.0f);
        float inter = wd * ht;
        float denom = fmaxf(ba + lar[j] - inter, 1e-9f);
        if (inter / denom > 0.7f) bits |= (1ull << (j - jbase));
      }
    }
    M[(size_t)i * MASK_STRIDE + w] = bits;
  }
  if (part == 0) {
    for (int i = tid; i < m; i += 256) pos_lvl[bl * 1024 + i] = lpos[i];
    if (tid < MASK_STRIDE) {
      unsigned long long vm = 0ull;
      for (int j = 0; j < 64; ++j) {
        int i = tid * 64 + j;
        if (i < m && lval[i]) vm |= (1ull << j);
      }
      validmask[bl * MASK_STRIDE + tid] = vm;
    }
  }
}

// ---------------------------------------------------------------------------
// K4b: serial bitmask scan, one wave per (batch,level).
// ---------------------------------------------------------------------------
__global__ __launch_bounds__(64) void k_scan(const unsigned long long* __restrict__ masks,
                                             const int* __restrict__ pos_lvl,
                                             const unsigned long long* __restrict__ validmask,
                                             int* __restrict__ keep_g) {
  int bl = blockIdx.x;
  int b = bl / NLEV, l = bl % NLEV;
  int lane = threadIdx.x;
  const int m = d_k[l];  // 1000 or 576 — both divisible by 8
  const unsigned long long* M = masks + (size_t)bl * 1024 * MASK_STRIDE;
  __shared__ unsigned char keep_lds[1024];
  unsigned long long remv = 0ull;
  if (lane < MASK_STRIDE) remv = ~validmask[bl * MASK_STRIDE + lane];  // invalid = pre-suppressed
  unsigned long long buf[8];
  bool owner = (lane < MASK_STRIDE);
  if (owner) {
#pragma unroll
    for (int u = 0; u < 8; ++u) buf[u] = M[(size_t)u * MASK_STRIDE + lane];
  }
  int nch = m / 8;
  for (int c = 0; c < nch; ++c) {
#pragma unroll
    for (int u = 0; u < 8; ++u) {
      int i = c * 8 + u;
      unsigned long long dw = __shfl(remv, i >> 6);
      int keep = (int)(((dw >> (i & 63)) & 1ull) ^ 1ull);
      if (owner) {
        if (keep) remv |= buf[u];
        int pi = i + 8;
        if (pi < m) buf[u] = M[(size_t)pi * MASK_STRIDE + lane];
      }
      if (lane == 0) keep_lds[i] = (unsigned char)keep;
    }
  }
  __syncthreads();
  for (int i = lane; i < m; i += 64)
    keep_g[b * KTOT + pos_lvl[bl * 1024 + i]] = keep_lds[i];
}

// ---------------------------------------------------------------------------
// K5: emit first 1000 kept (in global sorted order) per image; zero-pad rest
// ---------------------------------------------------------------------------
__global__ __launch_bounds__(256) void k_out(const float* __restrict__ boxes_sorted,
                                             const float* __restrict__ score_sorted,
                                             const int* __restrict__ keep_g,
                                             float* __restrict__ out) {
  int b = blockIdx.x, tid = threadIdx.x;
  __shared__ int s_wcnt[4], s_base;
  for (int i = tid; i < 5000; i += 256) out[(size_t)b * 5000 + i] = 0.0f;
  if (tid == 0) s_base = 0;
  __syncthreads();
  for (int chunk = 0; chunk < KTOT; chunk += 256) {
    int j = chunk + tid;
    bool match = (j < KTOT) && (keep_g[b * KTOT + j] != 0);
    unsigned long long mb = __ballot(match);
    if ((tid & 63) == 0) s_wcnt[tid >> 6] = __popcll(mb);
    __syncthreads();
    int rank = s_base + __popcll(mb & ((1ull << (tid & 63)) - 1ull));
    for (int w = 0; w < (tid >> 6); ++w) rank += s_wcnt[w];
    if (match && rank < 1000) {
      const float* bp = boxes_sorted + ((size_t)(b * KTOT + j)) * 4;
      float* op = out + ((size_t)(b * 1000 + rank)) * 5;
      op[0] = bp[0]; op[1] = bp[1]; op[2] = bp[2]; op[3] = bp[3];
      op[4] = score_sorted[b * KTOT + j];
    }
    __syncthreads();
    if (tid == 0) s_base += s_wcnt[0] + s_wcnt[1] + s_wcnt[2] + s_wcnt[3];
    __syncthreads();
  }
}

extern "C" void kernel_launch(void* const* d_in, const int* in_sizes, int n_in,
                              void* d_out, int out_size, void* d_ws, size_t ws_size,
                              hipStream_t stream) {
  const float* obj     = (const float*)d_in[0];
  const float* deltas  = (const float*)d_in[1];
  const float* anchors = (const float*)d_in[2];
  float* out = (float*)d_out;

  // workspace layout (~7.3 MB)
  int*   sel_idx      = (int*)d_ws;                          // [8*4576]
  float* boxes        = (float*)(sel_idx + BATCH * KTOT);    // [8*4576*4]
  float* sprime       = boxes + (size_t)BATCH * KTOT * 4;    // [8*4576]
  float* maxv         = sprime + BATCH * KTOT;               // [8]
  float* score_sorted = maxv + BATCH;                        // [8*4576]
  float* boxes_sorted = score_sorted + BATCH * KTOT;         // [8*4576*4]
  int*   lvl_sorted   = (int*)(boxes_sorted + (size_t)BATCH * KTOT * 4);  // [8*4576]
  int*   keep_g       = lvl_sorted + BATCH * KTOT;           // [8*4576]
  int*   pos_lvl      = keep_g + BATCH * KTOT;               // [40*1024]
  unsigned long long* validmask = (unsigned long long*)(((uintptr_t)(pos_lvl + BATCH * NLEV * 1024) + 15) & ~(uintptr_t)15);  // [40*16]
  unsigned long long* masks = validmask + BATCH * NLEV * MASK_STRIDE;      // [40*1024*16] = 5.24 MB

  hipLaunchKernelGGL(k_topk, dim3(BATCH * NLEV), dim3(1024), 0, stream, obj, sel_idx, maxv);
  hipLaunchKernelGGL(k_decode, dim3((BATCH * KTOT + 255) / 256), dim3(256), 0, stream,
                     obj, deltas, anchors, sel_idx, boxes, sprime, maxv);
  hipLaunchKernelGGL(k_sort, dim3(BATCH), dim3(1024), 0, stream,
                     sprime, boxes, score_sorted, boxes_sorted, lvl_sorted);
  hipLaunchKernelGGL(k_mask, dim3(BATCH * NLEV * SPLIT), dim3(256), 0, stream,
                     boxes_sorted, score_sorted, lvl_sorted, maxv, masks, pos_lvl, validmask);
  hipLaunchKernelGGL(k_scan, dim3(BATCH * NLEV), dim3(64), 0, stream,
                     masks, pos_lvl, validmask, keep_g);
  hipLaunchKernelGGL(k_out, dim3(BATCH), dim3(256), 0, stream,
                     boxes_sorted, score_sorted, keep_g, out);
}

// Round 4
// 607.008 us; speedup vs baseline: 2.4433x; 1.6051x over previous
//
#include <hip/hip_runtime.h>
#include <math.h>

#pragma clang fp contract(off)

#define A_TOTAL 196416
#define BATCH 8
#define KTOT 4576
#define NLEV 5
#define TB_CAP 4096      // top-k candidate buffer (worst observed need ~1.4k)

static __device__ const int d_aoff[NLEV] = {0, 147456, 184320, 193536, 195840};
static __device__ const int d_n[NLEV]    = {147456, 36864, 9216, 2304, 576};
static __device__ const int d_k[NLEV]    = {1000, 1000, 1000, 1000, 576};
static __device__ const int d_koff[NLEV] = {0, 1000, 2000, 3000, 4000};

// monotone map: f32 -> u32 preserving order (no NaNs in this data)
__device__ inline unsigned int mono(float f) {
  unsigned int u = __float_as_uint(f);
  return (u & 0x80000000u) ? ~u : (u | 0x80000000u);
}

// in-LDS bitonic ascending sort; all threads of the block must call
template <typename T>
__device__ inline void bitonic_sort(T* arr, int N, int tid, int nth) {
  for (int size = 2; size <= N; size <<= 1) {
    for (int stride = size >> 1; stride > 0; stride >>= 1) {
      __syncthreads();
      for (int e = tid; e < N; e += nth) {
        int partner = e ^ stride;
        if (partner > e) {
          T a = arr[e], b2 = arr[partner];
          bool up = ((e & size) == 0);
          if (up ? (a > b2) : (a < b2)) { arr[e] = b2; arr[partner] = a; }
        }
      }
    }
  }
  __syncthreads();
}

// ---------------------------------------------------------------------------
// K1: per (batch, level) exact top-k (lax.top_k semantics: value desc, idx asc)
// ---------------------------------------------------------------------------
__global__ __launch_bounds__(1024) void k_topk(const float* __restrict__ obj,
                                               int* __restrict__ sel_idx,
                                               float* __restrict__ maxv) {
  int bx = blockIdx.x;
  int b = bx / NLEV, l = bx % NLEV;
  int tid = threadIdx.x;
  if (tid == 0 && bx < BATCH) maxv[bx] = 0.0f;  // init for K2's atomicMax (coords >= 0)
  const int aoff = d_aoff[l], n = d_n[l], k = d_k[l], koff = d_koff[l];
  const float* ob = obj + (size_t)b * A_TOTAL + aoff;

  __shared__ int hist[4096];                    // 16 KB
  __shared__ unsigned long long buf[TB_CAP];    // 32 KB
  __shared__ int s_grp[256];
  __shared__ int s_cnt;
  __shared__ unsigned int s_P;

  for (int i = tid; i < 4096; i += 1024) hist[i] = 0;
  if (tid == 0) s_cnt = 0;
  __syncthreads();

  for (int i = tid; i < n; i += 1024) {
    unsigned int key = mono(ob[i]);
    atomicAdd(&hist[key >> 20], 1);
  }
  __syncthreads();
  // hierarchical threshold scan: 256 groups of 16 bins
  if (tid < 256) {
    int s = 0;
    for (int j = 0; j < 16; ++j) s += hist[tid * 16 + j];
    s_grp[tid] = s;
  }
  __syncthreads();
  if (tid == 0) {
    int cum = 0, g, d;
    for (g = 255; g >= 0; --g) {
      if (cum + s_grp[g] >= k) break;
      cum += s_grp[g];
    }
    for (d = 15; d >= 0; --d) {
      int c = hist[g * 16 + d];
      if (cum + c >= k) break;
      cum += c;
    }
    s_P = (unsigned int)(g * 16 + d);
  }
  __syncthreads();
  unsigned int P = s_P;  // count(prefix > P) < k <= count(prefix >= P)

  for (int i = tid; i < n; i += 1024) {
    unsigned int key = mono(ob[i]);
    if ((key >> 20) >= P) {
      int slot = atomicAdd(&s_cnt, 1);
      if (slot < TB_CAP)
        buf[slot] = ((unsigned long long)key << 32) | (unsigned int)(~(unsigned int)i);
    }
  }
  __syncthreads();
  int cnt = min(s_cnt, TB_CAP);
  for (int i = tid; i < TB_CAP; i += 1024) if (i >= cnt) buf[i] = 0ull;
  __syncthreads();
  bitonic_sort(buf, TB_CAP, tid, 1024);  // ascending (key asc, then idx desc)
  if (tid < k) {
    unsigned long long e = buf[TB_CAP - 1 - tid];  // rank tid: key desc, idx asc on ties
    unsigned int idx = ~(unsigned int)(e & 0xFFFFFFFFull);
    sel_idx[b * KTOT + koff + tid] = aoff + (int)idx;
  }
}

// ---------------------------------------------------------------------------
// K2: decode + clip + sigmoid + validity for the selected 8x4576 anchors.
// ---------------------------------------------------------------------------
__global__ __launch_bounds__(256) void k_decode(const float* __restrict__ obj,
                                                const float* __restrict__ deltas,
                                                const float* __restrict__ anchors,
                                                const int* __restrict__ sel_idx,
                                                float* __restrict__ boxes,
                                                float* __restrict__ sprime,
                                                float* __restrict__ maxv) {
  __shared__ unsigned int s_max[2];
  int g = blockIdx.x * 256 + threadIdx.x;
  int b0 = (blockIdx.x * 256) / KTOT;  // first batch this block touches
  if (threadIdx.x < 2) s_max[threadIdx.x] = 0u;
  __syncthreads();
  if (g < BATCH * KTOT) {
    int b = g / KTOT;
    int gidx = sel_idx[g];
    float o = obj[(size_t)b * A_TOTAL + gidx];
    const float* dl = deltas + ((size_t)b * A_TOTAL + gidx) * 4;
    const float* an = anchors + (size_t)gidx * 4;
    float a0 = an[0], a1 = an[1], a2 = an[2], a3 = an[3];
    float wa = a2 - a0, ha = a3 - a1;
    float cxa = a0 + 0.5f * wa, cya = a1 + 0.5f * ha;
    float dx = dl[0], dy = dl[1];
    const float CLIPV = 4.135166556742356f;  // log(1000/16)
    float dw = fminf(dl[2], CLIPV), dh = fminf(dl[3], CLIPV);
    float pcx = dx * wa + cxa;               // contract(off): separate mul+add like numpy
    float pcy = dy * ha + cya;
    float pw = (float)exp((double)dw) * wa;  // correctly-rounded f32 exp
    float ph = (float)exp((double)dh) * ha;
    float x1 = pcx - 0.5f * pw, y1 = pcy - 0.5f * ph;
    float x2 = pcx + 0.5f * pw, y2 = pcy + 0.5f * ph;
    x1 = fminf(fmaxf(x1, 0.0f), 1024.0f);
    x2 = fminf(fmaxf(x2, 0.0f), 1024.0f);
    y1 = fminf(fmaxf(y1, 0.0f), 768.0f);
    y2 = fminf(fmaxf(y2, 0.0f), 768.0f);
    boxes[(size_t)g * 4 + 0] = x1;
    boxes[(size_t)g * 4 + 1] = y1;
    boxes[(size_t)g * 4 + 2] = x2;
    boxes[(size_t)g * 4 + 3] = y2;
    float s = (float)(1.0 / (1.0 + exp(-(double)o)));  // correctly-rounded sigmoid
    bool valid = ((x2 - x1) >= 1.0f) && ((y2 - y1) >= 1.0f) && (s >= 0.0f);
    sprime[g] = valid ? s : -1.0f;
    float mx = fmaxf(fmaxf(x1, y1), fmaxf(x2, y2));
    atomicMax(&s_max[b - b0], __float_as_uint(mx));  // coords >= 0 -> uint order ok
  }
  __syncthreads();
  if (threadIdx.x < 2 && b0 + (int)threadIdx.x < BATCH)
    atomicMax((unsigned int*)&maxv[b0 + threadIdx.x], s_max[threadIdx.x]);
}

// ---------------------------------------------------------------------------
// K3: per-image stable sort of 4576 entries by (s' desc, pos asc); gather
// ---------------------------------------------------------------------------
__global__ __launch_bounds__(1024) void k_sort(const float* __restrict__ sprime,
                                               const float* __restrict__ boxes,
                                               float* __restrict__ score_sorted,
                                               float* __restrict__ boxes_sorted,
                                               int* __restrict__ lvl_sorted) {
  int b = blockIdx.x, tid = threadIdx.x;
  __shared__ unsigned long long skey[8192];  // 64 KB
  for (int e = tid; e < 8192; e += 1024) {
    if (e < KTOT) {
      unsigned int m = mono(sprime[b * KTOT + e]);
      skey[e] = ((unsigned long long)m << 32) | (unsigned int)(8191 - e);  // tie: smaller pos wins
    } else {
      skey[e] = 0ull;  // below mono(-1.0)
    }
  }
  __syncthreads();
  bitonic_sort(skey, 8192, tid, 1024);
  for (int j = tid; j < KTOT; j += 1024) {
    unsigned long long e = skey[8191 - j];  // rank j in descending order
    int p = 8191 - (int)(e & 0xFFFFFFFFull);
    score_sorted[b * KTOT + j] = sprime[b * KTOT + p];
    int lv = (p < 1000) ? 0 : (p < 2000) ? 1 : (p < 3000) ? 2 : (p < 4000) ? 3 : 4;
    lvl_sorted[b * KTOT + j] = lv;
    for (int c = 0; c < 4; ++c)
      boxes_sorted[((size_t)(b * KTOT + j)) * 4 + c] = boxes[((size_t)(b * KTOT + p)) * 4 + c];
  }
}

// ---------------------------------------------------------------------------
// K4: fused blocked NMS, one block per (batch,level). Per 64-position chunk:
//   A) diagonal 64x64 IoU bits D[j] (all 1024 threads share the work)
//   B) 64-step serial register scan within the chunk (one wave, LDS prefetch,
//      no shuffles) -> kept word
//   C) parallel suppression of all later positions vs this chunk's kept set
//      (IoU on the fly from LDS boxes; __ballot -> atomicOr into remv words)
// Cross-level IoU is exactly 0 (offset gap >= 1) -> levels independent.
// ---------------------------------------------------------------------------
__global__ __launch_bounds__(1024) void k_nms(const float* __restrict__ boxes_sorted,
                                              const float* __restrict__ score_sorted,
                                              const int* __restrict__ lvl_sorted,
                                              const float* __restrict__ maxv,
                                              int* __restrict__ keep_g) {
  int bl = blockIdx.x;
  int b = bl / NLEV, l = bl % NLEV;
  int tid = threadIdx.x;
  const int m = d_k[l];
  __shared__ float lx1[1024], ly1[1024], lx2[1024], ly2[1024], lar[1024];
  __shared__ int lval[1024], lpos[1024];
  __shared__ int s_wcnt[16], s_base;
  __shared__ unsigned long long s_D[72];       // 64 + 8 pad (prefetch overrun)
  __shared__ unsigned long long s_remv[16];
  __shared__ unsigned long long s_keptw;
  float off = (float)l * (maxv[b] + 1.0f);
  if (tid == 0) s_base = 0;
  __syncthreads();
  // ---- ordered compaction of this level's entries (in sorted order) ----
  for (int chunk = 0; chunk < KTOT; chunk += 1024) {
    int j = chunk + tid;
    bool match = (j < KTOT) && (lvl_sorted[b * KTOT + j] == l);
    unsigned long long mb = __ballot(match);
    if ((tid & 63) == 0) s_wcnt[tid >> 6] = __popcll(mb);
    __syncthreads();
    int rank = s_base + __popcll(mb & ((1ull << (tid & 63)) - 1ull));
    for (int w = 0; w < (tid >> 6); ++w) rank += s_wcnt[w];
    if (match) {
      const float* bp = boxes_sorted + ((size_t)(b * KTOT + j)) * 4;
      float x1 = bp[0] + off, y1 = bp[1] + off, x2 = bp[2] + off, y2 = bp[3] + off;
      lx1[rank] = x1; ly1[rank] = y1; lx2[rank] = x2; ly2[rank] = y2;
      lar[rank] = (x2 - x1) * (y2 - y1);
      lval[rank] = (score_sorted[b * KTOT + j] >= 0.0f) ? 1 : 0;
      lpos[rank] = j;
    }
    __syncthreads();
    if (tid == 0) {
      int s = 0;
      for (int w = 0; w < 16; ++w) s += s_wcnt[w];
      s_base += s;
    }
    __syncthreads();
  }
  // ---- validity words -> initial remv (invalid/out-of-range = suppressed) ----
  if (tid >= m) lval[tid] = 0;
  __syncthreads();
  {
    bool v = (lval[tid] != 0);
    unsigned long long vb = __ballot(v);
    if ((tid & 63) == 0) s_remv[tid >> 6] = ~vb;
  }
  __syncthreads();

  const int nch = (m + 63) / 64;
  for (int c = 0; c < nch; ++c) {
    // ---- phase A: diagonal block bits ----
    if (tid < 72) s_D[tid] = 0ull;
    __syncthreads();
    {
      int j = tid & 63, s = tid >> 6;
      int gi = 64 * c + j;
      if (gi < m) {
        float bx1 = lx1[gi], by1 = ly1[gi], bx2 = lx2[gi], by2 = ly2[gi], ba = lar[gi];
        unsigned long long bits = 0ull;
        for (int jp = j + 1 + s; jp < 64; jp += 16) {
          int gj = 64 * c + jp;
          if (gj < m) {
            float xx1 = fmaxf(bx1, lx1[gj]), yy1 = fmaxf(by1, ly1[gj]);
            float xx2 = fminf(bx2, lx2[gj]), yy2 = fminf(by2, ly2[gj]);
            float wd = fmaxf(xx2 - xx1, 0.0f), ht = fmaxf(yy2 - yy1, 0.0f);
            float inter = wd * ht;
            float denom = fmaxf(ba + lar[gj] - inter, 1e-9f);
            if (inter / denom > 0.7f) bits |= (1ull << jp);
          }
        }
        if (bits) {
          unsigned int lo = (unsigned int)bits, hi = (unsigned int)(bits >> 32);
          if (lo) atomicOr((unsigned int*)&s_D[j], lo);
          if (hi) atomicOr(((unsigned int*)&s_D[j]) + 1, hi);
        }
      }
    }
    __syncthreads();
    // ---- phase B: serial in-chunk scan (one wave, register chain) ----
    if (tid < 64) {
      unsigned long long dw = s_remv[c];
      unsigned long long pb[8];
#pragma unroll
      for (int u = 0; u < 8; ++u) pb[u] = s_D[u];
#pragma unroll
      for (int g = 0; g < 8; ++g) {
#pragma unroll
        for (int u = 0; u < 8; ++u) {
          int j = g * 8 + u;
          if (!((dw >> j) & 1ull)) dw |= pb[u];
          pb[u] = s_D[j + 8];  // decision-independent prefetch (padded)
        }
      }
      if (tid == 0) { s_remv[c] = dw; s_keptw = ~dw; }
    }
    __syncthreads();
    // ---- phase C: suppress later positions vs this chunk's kept set ----
    {
      int base2 = 64 * (c + 1);
      int p = base2 + tid;
      bool sup = false;
      if (p < m) {
        float px1 = lx1[p], py1 = ly1[p], px2 = lx2[p], py2 = ly2[p], pa = lar[p];
        unsigned long long W = s_keptw;
        while (W) {
          int i = __builtin_ctzll(W);
          W &= W - 1;
          int bi = 64 * c + i;
          float xx1 = fmaxf(lx1[bi], px1), yy1 = fmaxf(ly1[bi], py1);
          float xx2 = fminf(lx2[bi], px2), yy2 = fminf(ly2[bi], py2);
          float wd = fmaxf(xx2 - xx1, 0.0f), ht = fmaxf(yy2 - yy1, 0.0f);
          float inter = wd * ht;
          float denom = fmaxf(lar[bi] + pa - inter, 1e-9f);
          sup = sup || (inter / denom > 0.7f);
        }
      }
      unsigned long long mb = __ballot(sup);
      int w = tid >> 6;
      if ((tid & 63) == 0 && mb && (c + 1 + w) < 16) {
        unsigned int lo = (unsigned int)mb, hi = (unsigned int)(mb >> 32);
        if (lo) atomicOr((unsigned int*)&s_remv[c + 1 + w], lo);
        if (hi) atomicOr(((unsigned int*)&s_remv[c + 1 + w]) + 1, hi);
      }
    }
    __syncthreads();
  }
  // ---- emit keep flags in global sorted positions ----
  if (tid < m) {
    int keep = ((s_remv[tid >> 6] >> (tid & 63)) & 1ull) ? 0 : 1;
    keep_g[b * KTOT + lpos[tid]] = keep;
  }
}

// ---------------------------------------------------------------------------
// K5: emit first 1000 kept (in global sorted order) per image; zero-pad rest
// ---------------------------------------------------------------------------
__global__ __launch_bounds__(256) void k_out(const float* __restrict__ boxes_sorted,
                                             const float* __restrict__ score_sorted,
                                             const int* __restrict__ keep_g,
                                             float* __restrict__ out) {
  int b = blockIdx.x, tid = threadIdx.x;
  __shared__ int s_wcnt[4], s_base;
  for (int i = tid; i < 5000; i += 256) out[(size_t)b * 5000 + i] = 0.0f;
  if (tid == 0) s_base = 0;
  __syncthreads();
  for (int chunk = 0; chunk < KTOT; chunk += 256) {
    int j = chunk + tid;
    bool match = (j < KTOT) && (keep_g[b * KTOT + j] != 0);
    unsigned long long mb = __ballot(match);
    if ((tid & 63) == 0) s_wcnt[tid >> 6] = __popcll(mb);
    __syncthreads();
    int rank = s_base + __popcll(mb & ((1ull << (tid & 63)) - 1ull));
    for (int w = 0; w < (tid >> 6); ++w) rank += s_wcnt[w];
    if (match && rank < 1000) {
      const float* bp = boxes_sorted + ((size_t)(b * KTOT + j)) * 4;
      float* op = out + ((size_t)(b * 1000 + rank)) * 5;
      op[0] = bp[0]; op[1] = bp[1]; op[2] = bp[2]; op[3] = bp[3];
      op[4] = score_sorted[b * KTOT + j];
    }
    __syncthreads();
    if (tid == 0) s_base += s_wcnt[0] + s_wcnt[1] + s_wcnt[2] + s_wcnt[3];
    __syncthreads();
  }
}

extern "C" void kernel_launch(void* const* d_in, const int* in_sizes, int n_in,
                              void* d_out, int out_size, void* d_ws, size_t ws_size,
                              hipStream_t stream) {
  const float* obj     = (const float*)d_in[0];
  const float* deltas  = (const float*)d_in[1];
  const float* anchors = (const float*)d_in[2];
  float* out = (float*)d_out;

  // workspace layout (~2.1 MB)
  int*   sel_idx      = (int*)d_ws;                          // [8*4576]
  float* boxes        = (float*)(sel_idx + BATCH * KTOT);    // [8*4576*4]
  float* sprime       = boxes + (size_t)BATCH * KTOT * 4;    // [8*4576]
  float* maxv         = sprime + BATCH * KTOT;               // [8]
  float* score_sorted = maxv + BATCH;                        // [8*4576]
  float* boxes_sorted = score_sorted + BATCH * KTOT;         // [8*4576*4]
  int*   lvl_sorted   = (int*)(boxes_sorted + (size_t)BATCH * KTOT * 4);  // [8*4576]
  int*   keep_g       = lvl_sorted + BATCH * KTOT;           // [8*4576]

  hipLaunchKernelGGL(k_topk, dim3(BATCH * NLEV), dim3(1024), 0, stream, obj, sel_idx, maxv);
  hipLaunchKernelGGL(k_decode, dim3((BATCH * KTOT + 255) / 256), dim3(256), 0, stream,
                     obj, deltas, anchors, sel_idx, boxes, sprime, maxv);
  hipLaunchKernelGGL(k_sort, dim3(BATCH), dim3(1024), 0, stream,
                     sprime, boxes, score_sorted, boxes_sorted, lvl_sorted);
  hipLaunchKernelGGL(k_nms, dim3(BATCH * NLEV), dim3(1024), 0, stream,
                     boxes_sorted, score_sorted, lvl_sorted, maxv, keep_g);
  hipLaunchKernelGGL(k_out, dim3(BATCH), dim3(256), 0, stream,
                     boxes_sorted, score_sorted, keep_g, out);
}

// Round 5
// 457.067 us; speedup vs baseline: 3.2449x; 1.3280x over previous
//
#include <hip/hip_runtime.h>
#include <math.h>

#pragma clang fp contract(off)

#define A_TOTAL 196416
#define BATCH 8
#define KTOT 4576
#define NLEV 5
#define TB_CAP 4096      // top-k candidate buffer (worst observed need ~1.4k)

static __device__ const int d_aoff[NLEV] = {0, 147456, 184320, 193536, 195840};
static __device__ const int d_n[NLEV]    = {147456, 36864, 9216, 2304, 576};
static __device__ const int d_k[NLEV]    = {1000, 1000, 1000, 1000, 576};
static __device__ const int d_koff[NLEV] = {0, 1000, 2000, 3000, 4000};

// Exact-equivalence constant for "RN(inter/denom) > 0.7f":
//   RN(q) > 0.7f  <=>  q >= midpoint(0.7f, nextafter(0.7f))   (midpoint rounds
//   to even = nextafter)  <=>  inter >= TM * denom  exactly (product has <=49
//   significand bits -> exact in double).
#define TM_IOU (0.699999988079071044921875 + 0x1p-25)

// monotone map: f32 -> u32 preserving order (no NaNs in this data)
__device__ inline unsigned int mono(float f) {
  unsigned int u = __float_as_uint(f);
  return (u & 0x80000000u) ? ~u : (u | 0x80000000u);
}

// in-LDS bitonic ascending sort; all threads of the block must call
template <typename T>
__device__ inline void bitonic_sort(T* arr, int N, int tid, int nth) {
  for (int size = 2; size <= N; size <<= 1) {
    for (int stride = size >> 1; stride > 0; stride >>= 1) {
      __syncthreads();
      for (int e = tid; e < N; e += nth) {
        int partner = e ^ stride;
        if (partner > e) {
          T a = arr[e], b2 = arr[partner];
          bool up = ((e & size) == 0);
          if (up ? (a > b2) : (a < b2)) { arr[e] = b2; arr[partner] = a; }
        }
      }
    }
  }
  __syncthreads();
}

// binary searches on a descending-sorted array
__device__ inline int cnt_gt(const float* A, int n, float s) {  // #{A[i] > s}
  int lo = 0, hi = n;
  while (lo < hi) { int mid = (lo + hi) >> 1; if (A[mid] > s) lo = mid + 1; else hi = mid; }
  return lo;
}
__device__ inline int cnt_ge(const float* A, int n, float s) {  // #{A[i] >= s}
  int lo = 0, hi = n;
  while (lo < hi) { int mid = (lo + hi) >> 1; if (A[mid] >= s) lo = mid + 1; else hi = mid; }
  return lo;
}

// ---------------------------------------------------------------------------
// K1: per (batch, level) exact top-k (lax.top_k semantics: value desc, idx asc)
// ---------------------------------------------------------------------------
__global__ __launch_bounds__(1024) void k_topk(const float* __restrict__ obj,
                                               int* __restrict__ sel_idx,
                                               float* __restrict__ maxv) {
  int bx = blockIdx.x;
  int b = bx / NLEV, l = bx % NLEV;
  int tid = threadIdx.x;
  if (tid == 0 && bx < BATCH) maxv[bx] = 0.0f;  // init for K2's atomicMax (coords >= 0)
  const int aoff = d_aoff[l], n = d_n[l], k = d_k[l], koff = d_koff[l];
  const float* ob = obj + (size_t)b * A_TOTAL + aoff;

  __shared__ int hist[4096];                    // 16 KB
  __shared__ unsigned long long buf[TB_CAP];    // 32 KB
  __shared__ int s_grp[256];
  __shared__ int s_cnt;
  __shared__ unsigned int s_P;

  for (int i = tid; i < 4096; i += 1024) hist[i] = 0;
  if (tid == 0) s_cnt = 0;
  __syncthreads();

  for (int i = tid; i < n; i += 1024) {
    unsigned int key = mono(ob[i]);
    atomicAdd(&hist[key >> 20], 1);
  }
  __syncthreads();
  if (tid < 256) {
    int s = 0;
    for (int j = 0; j < 16; ++j) s += hist[tid * 16 + j];
    s_grp[tid] = s;
  }
  __syncthreads();
  if (tid == 0) {
    int cum = 0, g, d;
    for (g = 255; g >= 0; --g) {
      if (cum + s_grp[g] >= k) break;
      cum += s_grp[g];
    }
    for (d = 15; d >= 0; --d) {
      int c = hist[g * 16 + d];
      if (cum + c >= k) break;
      cum += c;
    }
    s_P = (unsigned int)(g * 16 + d);
  }
  __syncthreads();
  unsigned int P = s_P;  // count(prefix > P) < k <= count(prefix >= P)

  for (int i = tid; i < n; i += 1024) {
    unsigned int key = mono(ob[i]);
    if ((key >> 20) >= P) {
      int slot = atomicAdd(&s_cnt, 1);
      if (slot < TB_CAP)
        buf[slot] = ((unsigned long long)key << 32) | (unsigned int)(~(unsigned int)i);
    }
  }
  __syncthreads();
  int cnt = min(s_cnt, TB_CAP);
  for (int i = tid; i < TB_CAP; i += 1024) if (i >= cnt) buf[i] = 0ull;
  __syncthreads();
  bitonic_sort(buf, TB_CAP, tid, 1024);  // ascending (key asc, then idx desc)
  if (tid < k) {
    unsigned long long e = buf[TB_CAP - 1 - tid];  // rank tid: key desc, idx asc on ties
    unsigned int idx = ~(unsigned int)(e & 0xFFFFFFFFull);
    sel_idx[b * KTOT + koff + tid] = aoff + (int)idx;
  }
}

// ---------------------------------------------------------------------------
// K2: decode + clip + sigmoid + validity for the selected 8x4576 anchors.
// ---------------------------------------------------------------------------
__global__ __launch_bounds__(256) void k_decode(const float* __restrict__ obj,
                                                const float* __restrict__ deltas,
                                                const float* __restrict__ anchors,
                                                const int* __restrict__ sel_idx,
                                                float* __restrict__ boxes,
                                                float* __restrict__ sprime,
                                                float* __restrict__ maxv) {
  __shared__ unsigned int s_max[2];
  int g = blockIdx.x * 256 + threadIdx.x;
  int b0 = (blockIdx.x * 256) / KTOT;  // first batch this block touches
  if (threadIdx.x < 2) s_max[threadIdx.x] = 0u;
  __syncthreads();
  if (g < BATCH * KTOT) {
    int b = g / KTOT;
    int gidx = sel_idx[g];
    float o = obj[(size_t)b * A_TOTAL + gidx];
    const float* dl = deltas + ((size_t)b * A_TOTAL + gidx) * 4;
    const float* an = anchors + (size_t)gidx * 4;
    float a0 = an[0], a1 = an[1], a2 = an[2], a3 = an[3];
    float wa = a2 - a0, ha = a3 - a1;
    float cxa = a0 + 0.5f * wa, cya = a1 + 0.5f * ha;
    float dx = dl[0], dy = dl[1];
    const float CLIPV = 4.135166556742356f;  // log(1000/16)
    float dw = fminf(dl[2], CLIPV), dh = fminf(dl[3], CLIPV);
    float pcx = dx * wa + cxa;               // contract(off): separate mul+add like numpy
    float pcy = dy * ha + cya;
    float pw = (float)exp((double)dw) * wa;  // correctly-rounded f32 exp
    float ph = (float)exp((double)dh) * ha;
    float x1 = pcx - 0.5f * pw, y1 = pcy - 0.5f * ph;
    float x2 = pcx + 0.5f * pw, y2 = pcy + 0.5f * ph;
    x1 = fminf(fmaxf(x1, 0.0f), 1024.0f);
    x2 = fminf(fmaxf(x2, 0.0f), 1024.0f);
    y1 = fminf(fmaxf(y1, 0.0f), 768.0f);
    y2 = fminf(fmaxf(y2, 0.0f), 768.0f);
    boxes[(size_t)g * 4 + 0] = x1;
    boxes[(size_t)g * 4 + 1] = y1;
    boxes[(size_t)g * 4 + 2] = x2;
    boxes[(size_t)g * 4 + 3] = y2;
    float s = (float)(1.0 / (1.0 + exp(-(double)o)));  // correctly-rounded sigmoid
    bool valid = ((x2 - x1) >= 1.0f) && ((y2 - y1) >= 1.0f) && (s >= 0.0f);
    sprime[g] = valid ? s : -1.0f;
    float mx = fmaxf(fmaxf(x1, y1), fmaxf(x2, y2));
    atomicMax(&s_max[b - b0], __float_as_uint(mx));  // coords >= 0 -> uint order ok
  }
  __syncthreads();
  if (threadIdx.x < 2 && b0 + (int)threadIdx.x < BATCH)
    atomicMax((unsigned int*)&maxv[b0 + threadIdx.x], s_max[threadIdx.x]);
}

// ---------------------------------------------------------------------------
// K3: merge-rank stable sort (replaces bitonic(8192)). Per-level valid scores
// are already sorted desc with pos-asc ties (topk order); invalids are -1.
// Global stable order = 5-way merge of valid runs (tie: lower level/pos first)
// followed by invalids in pos order. Each element's global rank = local rank +
// sum over other levels of cnt_ge (earlier levels) / cnt_gt (later levels).
// ---------------------------------------------------------------------------
__global__ __launch_bounds__(1024) void k_merge(const float* __restrict__ sprime,
                                                const float* __restrict__ boxes,
                                                float* __restrict__ score_sorted,
                                                float* __restrict__ boxes_sorted,
                                                int* __restrict__ lvl_sorted) {
  int b = blockIdx.x, tid = threadIdx.x, lane = tid & 63, wv = tid >> 6;
  __shared__ float s_sc[KTOT];   // compacted valid scores, at level offsets
  __shared__ int s_src[KTOT];    // valid: level-local original index
  __shared__ int s_iv[KTOT];     // invalid: level-local original index
  __shared__ int s_V[NLEV];
  __shared__ int s_wcnt[16];

  for (int l = 0; l < NLEV; ++l) {
    int koff = d_koff[l], k = d_k[l];
    bool in = tid < k;
    float s = in ? sprime[(size_t)b * KTOT + koff + tid] : -1.0f;
    bool valid = in && (s >= 0.0f);
    unsigned long long mb = __ballot(valid);
    if (lane == 0) s_wcnt[wv] = __popcll(mb);
    __syncthreads();
    int pre = 0;
    for (int w = 0; w < wv; ++w) pre += s_wcnt[w];
    int vrank = pre + __popcll(mb & ((1ull << lane) - 1ull));
    if (valid) { s_sc[koff + vrank] = s; s_src[koff + vrank] = tid; }
    if (in && !valid) s_iv[koff + (tid - vrank)] = tid;
    if (tid == 0) {
      int t = 0;
      for (int w = 0; w < 16; ++w) t += s_wcnt[w];
      s_V[l] = t;
    }
    __syncthreads();
  }
  int V[NLEV], VT = 0;
  for (int l = 0; l < NLEV; ++l) { V[l] = s_V[l]; VT += V[l]; }
  int IOff[NLEV];
  { int run = VT; for (int l = 0; l < NLEV; ++l) { IOff[l] = run; run += d_k[l] - V[l]; } }

  for (int e = tid; e < KTOT; e += 1024) {
    int le = (e < 1000) ? 0 : (e < 2000) ? 1 : (e < 3000) ? 2 : (e < 4000) ? 3 : 4;
    int koff = d_koff[le];
    int i = e - koff;
    int rank, srcpos;
    float sval;
    if (i < V[le]) {
      float s = s_sc[e];
      rank = i;
      for (int l2 = 0; l2 < NLEV; ++l2) {
        if (l2 == le) continue;
        const float* A = s_sc + d_koff[l2];
        rank += (l2 < le) ? cnt_ge(A, V[l2], s) : cnt_gt(A, V[l2], s);
      }
      srcpos = koff + s_src[e];
      sval = s;
    } else {
      int j = i - V[le];
      rank = IOff[le] + j;
      srcpos = koff + s_iv[koff + j];
      sval = -1.0f;
    }
    score_sorted[(size_t)b * KTOT + rank] = sval;
    lvl_sorted[b * KTOT + rank] = le;
    const float* bp = boxes + ((size_t)(b * KTOT + srcpos)) * 4;
    float* op = boxes_sorted + ((size_t)(b * KTOT + rank)) * 4;
    op[0] = bp[0]; op[1] = bp[1]; op[2] = bp[2]; op[3] = bp[3];
  }
}

// ---------------------------------------------------------------------------
// K4: fused blocked NMS v2 — thread tid owns position tid; wave c == chunk c.
// Per chunk: A) distributed diagonal bits + ballot of own-wave sup word;
// B) 64-step serial register scan (wave 0, LDS-prefetched); C) later waves
// test their (not-yet-suppressed) position against the chunk's kept boxes.
// IoU test is the exact division-free double compare (see TM_IOU).
// ---------------------------------------------------------------------------
__global__ __launch_bounds__(1024) void k_nms(const float* __restrict__ boxes_sorted,
                                              const float* __restrict__ score_sorted,
                                              const int* __restrict__ lvl_sorted,
                                              const float* __restrict__ maxv,
                                              int* __restrict__ keep_g) {
  int bl = blockIdx.x;
  int b = bl / NLEV, l = bl % NLEV;
  int tid = threadIdx.x, lane = tid & 63, wv = tid >> 6;
  const int m = d_k[l];
  __shared__ float4 lbox[1024];
  __shared__ float lar[1024];
  __shared__ int lpos[1024];     // >=0: valid orig pos; <0: ~pos (invalid)
  __shared__ int s_wcnt[16];
  __shared__ int s_base;
  __shared__ unsigned long long s_D[72];  // 64 + 8 pad (phase-B prefetch)
  __shared__ unsigned long long s_w0, s_dw;
  float off = (float)l * (maxv[b] + 1.0f);
  if (tid == 0) s_base = 0;
  if (tid < 72) s_D[tid] = 0ull;
  __syncthreads();
  // ---- ordered compaction of this level's entries (in sorted order) ----
  for (int chunk = 0; chunk < KTOT; chunk += 1024) {
    int j = chunk + tid;
    bool match = (j < KTOT) && (lvl_sorted[b * KTOT + j] == l);
    unsigned long long mb = __ballot(match);
    if (lane == 0) s_wcnt[wv] = __popcll(mb);
    __syncthreads();
    int rank = s_base + __popcll(mb & ((1ull << lane) - 1ull));
    for (int w = 0; w < wv; ++w) rank += s_wcnt[w];
    if (match) {
      const float* bp = boxes_sorted + ((size_t)(b * KTOT + j)) * 4;
      float x1 = bp[0] + off, y1 = bp[1] + off, x2 = bp[2] + off, y2 = bp[3] + off;
      lbox[rank] = make_float4(x1, y1, x2, y2);
      lar[rank] = (x2 - x1) * (y2 - y1);
      lpos[rank] = (score_sorted[b * KTOT + j] >= 0.0f) ? j : ~j;
    }
    __syncthreads();
    if (tid == 0) {
      int s = 0;
      for (int w = 0; w < 16; ++w) s += s_wcnt[w];
      s_base += s;
    }
    __syncthreads();
  }
  // ---- own state ----
  bool active = (tid < m);
  float4 mybox = make_float4(0.f, 0.f, 0.f, 0.f);
  float myar = 0.f;
  bool sup = true;
  if (active) { mybox = lbox[tid]; myar = lar[tid]; sup = (lpos[tid] < 0); }

  const int nch = (m + 63) / 64;
  for (int c = 0; c < nch; ++c) {
    int base = c * 64;
    // ---- phase A: own-wave sup ballot + distributed diagonal bits ----
    if (wv == c) {
      unsigned long long mbv = __ballot(sup);
      if (lane == 0) s_w0 = mbv;
    }
    {
      int gi = base + lane;
      if (gi < m) {
        float4 bb = lbox[gi];
        float ba = lar[gi];
        unsigned long long bits = 0ull;
        for (int jp = lane + 1 + wv; jp < 64; jp += 16) {
          int gj = base + jp;
          if (gj < m) {
            float4 cb = lbox[gj];
            float xx1 = fmaxf(bb.x, cb.x), yy1 = fmaxf(bb.y, cb.y);
            float xx2 = fminf(bb.z, cb.z), yy2 = fminf(bb.w, cb.w);
            float wd = fmaxf(xx2 - xx1, 0.0f), ht = fmaxf(yy2 - yy1, 0.0f);
            float inter = wd * ht;
            float denom = fmaxf(ba + lar[gj] - inter, 1e-9f);
            if ((double)inter >= TM_IOU * (double)denom) bits |= (1ull << jp);
          }
        }
        if (bits) {
          unsigned int lo = (unsigned int)bits, hi = (unsigned int)(bits >> 32);
          if (lo) atomicOr((unsigned int*)&s_D[lane], lo);
          if (hi) atomicOr(((unsigned int*)&s_D[lane]) + 1, hi);
        }
      }
    }
    __syncthreads();
    // ---- phase B: serial in-chunk scan (wave 0, redundant lanes, prefetch) ----
    if (tid < 64) {
      unsigned long long dw = s_w0;
      unsigned long long pb[8];
#pragma unroll
      for (int u = 0; u < 8; ++u) pb[u] = s_D[u];
#pragma unroll
      for (int g = 0; g < 8; ++g) {
#pragma unroll
        for (int u = 0; u < 8; ++u) {
          int j = g * 8 + u;
          if (!((dw >> j) & 1ull)) dw |= pb[u];
          pb[u] = s_D[j + 8];  // decision-independent prefetch (padded)
        }
      }
      if (tid == 0) s_dw = dw;
    }
    __syncthreads();
    // ---- phase C: resolve own wave; later waves test vs kept set ----
    if (wv == c && active) sup = ((s_dw >> lane) & 1ull) != 0ull;
    unsigned long long K = ~s_dw;  // kept word (uniform)
    if (wv > c) {
      bool any = (__ballot(!sup) != 0ull);
      if (any && !sup) {
        unsigned long long W = K;
        while (W) {
          int j = __builtin_ctzll(W);
          W &= W - 1;
          float4 bb = lbox[base + j];
          float ba = lar[base + j];
          float xx1 = fmaxf(bb.x, mybox.x), yy1 = fmaxf(bb.y, mybox.y);
          float xx2 = fminf(bb.z, mybox.z), yy2 = fminf(bb.w, mybox.w);
          float wd = fmaxf(xx2 - xx1, 0.0f), ht = fmaxf(yy2 - yy1, 0.0f);
          float inter = wd * ht;
          float denom = fmaxf(ba + myar - inter, 1e-9f);
          if ((double)inter >= TM_IOU * (double)denom) { sup = true; break; }
        }
      }
    }
    if (tid < 64) s_D[tid] = 0ull;  // clear for next chunk (wave 0 is idle in C)
    __syncthreads();
  }
  // ---- emit keep flags in global sorted positions ----
  if (active) {
    int p = (lpos[tid] < 0) ? ~lpos[tid] : lpos[tid];
    keep_g[b * KTOT + p] = sup ? 0 : 1;
  }
}

// ---------------------------------------------------------------------------
// K5: emit first 1000 kept (in global sorted order) per image; zero-pad rest
// ---------------------------------------------------------------------------
__global__ __launch_bounds__(256) void k_out(const float* __restrict__ boxes_sorted,
                                             const float* __restrict__ score_sorted,
                                             const int* __restrict__ keep_g,
                                             float* __restrict__ out) {
  int b = blockIdx.x, tid = threadIdx.x;
  __shared__ int s_wcnt[4], s_base;
  for (int i = tid; i < 5000; i += 256) out[(size_t)b * 5000 + i] = 0.0f;
  if (tid == 0) s_base = 0;
  __syncthreads();
  for (int chunk = 0; chunk < KTOT; chunk += 256) {
    int j = chunk + tid;
    bool match = (j < KTOT) && (keep_g[b * KTOT + j] != 0);
    unsigned long long mb = __ballot(match);
    if ((tid & 63) == 0) s_wcnt[tid >> 6] = __popcll(mb);
    __syncthreads();
    int rank = s_base + __popcll(mb & ((1ull << (tid & 63)) - 1ull));
    for (int w = 0; w < (tid >> 6); ++w) rank += s_wcnt[w];
    if (match && rank < 1000) {
      const float* bp = boxes_sorted + ((size_t)(b * KTOT + j)) * 4;
      float* op = out + ((size_t)(b * 1000 + rank)) * 5;
      op[0] = bp[0]; op[1] = bp[1]; op[2] = bp[2]; op[3] = bp[3];
      op[4] = score_sorted[b * KTOT + j];
    }
    __syncthreads();
    if (tid == 0) s_base += s_wcnt[0] + s_wcnt[1] + s_wcnt[2] + s_wcnt[3];
    __syncthreads();
  }
}

extern "C" void kernel_launch(void* const* d_in, const int* in_sizes, int n_in,
                              void* d_out, int out_size, void* d_ws, size_t ws_size,
                              hipStream_t stream) {
  const float* obj     = (const float*)d_in[0];
  const float* deltas  = (const float*)d_in[1];
  const float* anchors = (const float*)d_in[2];
  float* out = (float*)d_out;

  // workspace layout (~2.1 MB)
  int*   sel_idx      = (int*)d_ws;                          // [8*4576]
  float* boxes        = (float*)(sel_idx + BATCH * KTOT);    // [8*4576*4]
  float* sprime       = boxes + (size_t)BATCH * KTOT * 4;    // [8*4576]
  float* maxv         = sprime + BATCH * KTOT;               // [8]
  float* score_sorted = maxv + BATCH;                        // [8*4576]
  float* boxes_sorted = score_sorted + BATCH * KTOT;         // [8*4576*4]
  int*   lvl_sorted   = (int*)(boxes_sorted + (size_t)BATCH * KTOT * 4);  // [8*4576]
  int*   keep_g       = lvl_sorted + BATCH * KTOT;           // [8*4576]

  hipLaunchKernelGGL(k_topk, dim3(BATCH * NLEV), dim3(1024), 0, stream, obj, sel_idx, maxv);
  hipLaunchKernelGGL(k_decode, dim3((BATCH * KTOT + 255) / 256), dim3(256), 0, stream,
                     obj, deltas, anchors, sel_idx, boxes, sprime, maxv);
  hipLaunchKernelGGL(k_merge, dim3(BATCH), dim3(1024), 0, stream,
                     sprime, boxes, score_sorted, boxes_sorted, lvl_sorted);
  hipLaunchKernelGGL(k_nms, dim3(BATCH * NLEV), dim3(1024), 0, stream,
                     boxes_sorted, score_sorted, lvl_sorted, maxv, keep_g);
  hipLaunchKernelGGL(k_out, dim3(BATCH), dim3(256), 0, stream,
                     boxes_sorted, score_sorted, keep_g, out);
}

// Round 6
// 361.123 us; speedup vs baseline: 4.1070x; 1.2657x over previous
//
#include <hip/hip_runtime.h>
#include <math.h>

#pragma clang fp contract(off)

#define A_TOTAL 196416
#define BATCH 8
#define KTOT 4576
#define NLEV 5
#define TB_CAP 2048

static __device__ const int d_aoff[NLEV] = {0, 147456, 184320, 193536, 195840};
static __device__ const int d_n[NLEV]    = {147456, 36864, 9216, 2304, 576};
static __device__ const int d_k[NLEV]    = {1000, 1000, 1000, 1000, 576};
static __device__ const int d_koff[NLEV] = {0, 1000, 2000, 3000, 4000};

// Exact-equivalence constant for "RN(inter/denom) > 0.7f":
//   RN(q) > 0.7f  <=>  q >= midpoint(0.7f, nextafter(0.7f))  <=>
//   (double)inter >= TM_IOU * (double)denom  exactly (<=49 sig bits).
#define TM_IOU (0.699999988079071044921875 + 0x1p-25)

// monotone map: f32 -> u32 preserving order (no NaNs in this data)
__device__ inline unsigned int mono(float f) {
  unsigned int u = __float_as_uint(f);
  return (u & 0x80000000u) ? ~u : (u | 0x80000000u);
}

// in-LDS bitonic ascending sort; all threads of the block must call
template <typename T>
__device__ inline void bitonic_sort(T* arr, int N, int tid, int nth) {
  for (int size = 2; size <= N; size <<= 1) {
    for (int stride = size >> 1; stride > 0; stride >>= 1) {
      __syncthreads();
      for (int e = tid; e < N; e += nth) {
        int partner = e ^ stride;
        if (partner > e) {
          T a = arr[e], b2 = arr[partner];
          bool up = ((e & size) == 0);
          if (up ? (a > b2) : (a < b2)) { arr[e] = b2; arr[partner] = a; }
        }
      }
    }
  }
  __syncthreads();
}

// binary searches on a descending-sorted array
__device__ inline int cnt_gt(const float* A, int n, float s) {  // #{A[i] > s}
  int lo = 0, hi = n;
  while (lo < hi) { int mid = (lo + hi) >> 1; if (A[mid] > s) lo = mid + 1; else hi = mid; }
  return lo;
}
__device__ inline int cnt_ge(const float* A, int n, float s) {  // #{A[i] >= s}
  int lo = 0, hi = n;
  while (lo < hi) { int mid = (lo + hi) >> 1; if (A[mid] >= s) lo = mid + 1; else hi = mid; }
  return lo;
}

// ---------------------------------------------------------------------------
// K1: per (batch, level) exact top-k (lax.top_k semantics: value desc, idx asc)
// 12-bit histogram -> exact candidate count; collect (cap 2048, 20-bit refine
// pass only if needed); adaptive-size bitonic sort of candidates.
// ---------------------------------------------------------------------------
__global__ __launch_bounds__(1024) void k_topk(const float* __restrict__ obj,
                                               int* __restrict__ sel_idx,
                                               float* __restrict__ maxv) {
  int bx = blockIdx.x;
  int b = bx / NLEV, l = bx % NLEV;
  int tid = threadIdx.x;
  if (tid == 0 && bx < BATCH) maxv[bx] = 0.0f;  // init for K2's atomicMax (coords >= 0)
  const int aoff = d_aoff[l], n = d_n[l], k = d_k[l], koff = d_koff[l];
  const float4* ob4 = (const float4*)(obj + (size_t)b * A_TOTAL + aoff);
  const int n4 = n >> 2;  // all level sizes divisible by 4

  __shared__ int hist[4096];                    // 16 KB
  __shared__ unsigned long long buf[TB_CAP];    // 16 KB
  __shared__ int s_grp[256];
  __shared__ int s_cnt;
  __shared__ int s_P12, s_ngt, s_cnt12;
  __shared__ unsigned int s_T20;

  for (int i = tid; i < 4096; i += 1024) hist[i] = 0;
  if (tid == 0) s_cnt = 0;
  __syncthreads();

  for (int i = tid; i < n4; i += 1024) {
    float4 v = ob4[i];
    atomicAdd(&hist[mono(v.x) >> 20], 1);
    atomicAdd(&hist[mono(v.y) >> 20], 1);
    atomicAdd(&hist[mono(v.z) >> 20], 1);
    atomicAdd(&hist[mono(v.w) >> 20], 1);
  }
  __syncthreads();
  if (tid < 256) {
    int s = 0;
    for (int j = 0; j < 16; ++j) s += hist[tid * 16 + j];
    s_grp[tid] = s;
  }
  __syncthreads();
  if (tid == 0) {
    int cum = 0, g, d;
    for (g = 255; g >= 0; --g) {
      if (cum + s_grp[g] >= k) break;
      cum += s_grp[g];
    }
    for (d = 15; d >= 0; --d) {
      int c = hist[g * 16 + d];
      if (cum + c >= k) break;
      cum += c;
    }
    int P12 = g * 16 + d;
    s_P12 = P12;
    s_ngt = cum;                 // count(prefix > P12)
    s_cnt12 = cum + hist[P12];   // count(prefix >= P12) — exact candidate count
    s_T20 = ((unsigned int)P12) << 8;
  }
  __syncthreads();

  if (s_cnt12 > TB_CAP) {
    // refine threshold by 8 more bits (extra scan; not hit on this data)
    unsigned int P12 = (unsigned int)s_P12;
    for (int i = tid; i < 256; i += 1024) hist[i] = 0;
    __syncthreads();
    for (int i = tid; i < n4; i += 1024) {
      float4 v = ob4[i];
      unsigned int a0 = mono(v.x), a1 = mono(v.y), a2 = mono(v.z), a3 = mono(v.w);
      if ((a0 >> 20) == P12) atomicAdd(&hist[(a0 >> 12) & 255], 1);
      if ((a1 >> 20) == P12) atomicAdd(&hist[(a1 >> 12) & 255], 1);
      if ((a2 >> 20) == P12) atomicAdd(&hist[(a2 >> 12) & 255], 1);
      if ((a3 >> 20) == P12) atomicAdd(&hist[(a3 >> 12) & 255], 1);
    }
    __syncthreads();
    if (tid == 0) {
      int cum = s_ngt, d;
      for (d = 255; d >= 0; --d) {
        int c = hist[d];
        if (cum + c >= k) break;
        cum += c;
      }
      s_T20 = (((unsigned int)s_P12) << 8) | (unsigned int)d;
    }
    __syncthreads();
  }
  unsigned int T20 = s_T20;

  for (int i = tid; i < n4; i += 1024) {
    float4 v = ob4[i];
    unsigned int kk[4] = {mono(v.x), mono(v.y), mono(v.z), mono(v.w)};
#pragma unroll
    for (int c = 0; c < 4; ++c) {
      if ((kk[c] >> 12) >= T20) {
        int slot = atomicAdd(&s_cnt, 1);
        if (slot < TB_CAP)
          buf[slot] = ((unsigned long long)kk[c] << 32) |
                      (unsigned int)(~(unsigned int)(4 * i + c));
      }
    }
  }
  __syncthreads();
  int cnt = min(s_cnt, TB_CAP);
  int N = (cnt <= 1024) ? 1024 : 2048;  // k <= 1000 < 1024 always
  for (int i = tid; i < N; i += 1024) if (i >= cnt) buf[i] = 0ull;
  __syncthreads();
  bitonic_sort(buf, N, tid, 1024);  // ascending (key asc, then idx desc)
  if (tid < k) {
    unsigned long long e = buf[N - 1 - tid];  // rank tid: key desc, idx asc on ties
    unsigned int idx = ~(unsigned int)(e & 0xFFFFFFFFull);
    sel_idx[b * KTOT + koff + tid] = aoff + (int)idx;
  }
}

// ---------------------------------------------------------------------------
// K2: decode + clip + sigmoid + validity for the selected 8x4576 anchors.
// ---------------------------------------------------------------------------
__global__ __launch_bounds__(256) void k_decode(const float* __restrict__ obj,
                                                const float* __restrict__ deltas,
                                                const float* __restrict__ anchors,
                                                const int* __restrict__ sel_idx,
                                                float* __restrict__ boxes,
                                                float* __restrict__ sprime,
                                                float* __restrict__ maxv) {
  __shared__ unsigned int s_max[2];
  int g = blockIdx.x * 256 + threadIdx.x;
  int b0 = (blockIdx.x * 256) / KTOT;  // first batch this block touches
  if (threadIdx.x < 2) s_max[threadIdx.x] = 0u;
  __syncthreads();
  if (g < BATCH * KTOT) {
    int b = g / KTOT;
    int gidx = sel_idx[g];
    float o = obj[(size_t)b * A_TOTAL + gidx];
    const float* dl = deltas + ((size_t)b * A_TOTAL + gidx) * 4;
    const float* an = anchors + (size_t)gidx * 4;
    float a0 = an[0], a1 = an[1], a2 = an[2], a3 = an[3];
    float wa = a2 - a0, ha = a3 - a1;
    float cxa = a0 + 0.5f * wa, cya = a1 + 0.5f * ha;
    float dx = dl[0], dy = dl[1];
    const float CLIPV = 4.135166556742356f;  // log(1000/16)
    float dw = fminf(dl[2], CLIPV), dh = fminf(dl[3], CLIPV);
    float pcx = dx * wa + cxa;               // contract(off): separate mul+add like numpy
    float pcy = dy * ha + cya;
    float pw = (float)exp((double)dw) * wa;  // correctly-rounded f32 exp
    float ph = (float)exp((double)dh) * ha;
    float x1 = pcx - 0.5f * pw, y1 = pcy - 0.5f * ph;
    float x2 = pcx + 0.5f * pw, y2 = pcy + 0.5f * ph;
    x1 = fminf(fmaxf(x1, 0.0f), 1024.0f);
    x2 = fminf(fmaxf(x2, 0.0f), 1024.0f);
    y1 = fminf(fmaxf(y1, 0.0f), 768.0f);
    y2 = fminf(fmaxf(y2, 0.0f), 768.0f);
    boxes[(size_t)g * 4 + 0] = x1;
    boxes[(size_t)g * 4 + 1] = y1;
    boxes[(size_t)g * 4 + 2] = x2;
    boxes[(size_t)g * 4 + 3] = y2;
    float s = (float)(1.0 / (1.0 + exp(-(double)o)));  // correctly-rounded sigmoid
    bool valid = ((x2 - x1) >= 1.0f) && ((y2 - y1) >= 1.0f) && (s >= 0.0f);
    sprime[g] = valid ? s : -1.0f;
    float mx = fmaxf(fmaxf(x1, y1), fmaxf(x2, y2));
    atomicMax(&s_max[b - b0], __float_as_uint(mx));  // coords >= 0 -> uint order ok
  }
  __syncthreads();
  if (threadIdx.x < 2 && b0 + (int)threadIdx.x < BATCH)
    atomicMax((unsigned int*)&maxv[b0 + threadIdx.x], s_max[threadIdx.x]);
}

// ---------------------------------------------------------------------------
// K3: merge-rank stable sort + NMS pre-compaction. Per-level valid scores are
// already desc-sorted (topk order); global stable order = 5-way merge of valid
// runs, then invalids in pos order. Also emits, per (b,l):
//   lvlbox  — level-compacted boxes in NMS scan order, offset-added (float4)
//   lvlrank — level rank -> global sorted rank
//   g_V     — number of valid entries (scan init: rank >= V -> suppressed)
// ---------------------------------------------------------------------------
__global__ __launch_bounds__(1024) void k_merge(const float* __restrict__ sprime,
                                                const float* __restrict__ boxes,
                                                const float* __restrict__ maxv,
                                                float* __restrict__ score_sorted,
                                                float* __restrict__ boxes_sorted,
                                                int* __restrict__ lvl_sorted,
                                                float4* __restrict__ lvlbox,
                                                int* __restrict__ lvlrank,
                                                int* __restrict__ g_V) {
  int b = blockIdx.x, tid = threadIdx.x, lane = tid & 63, wv = tid >> 6;
  __shared__ float s_sc[KTOT];   // compacted valid scores, at level offsets
  __shared__ int s_src[KTOT];    // valid: level-local original index
  __shared__ int s_iv[KTOT];     // invalid: level-local original index
  __shared__ int s_V[NLEV];
  __shared__ int s_wcnt[16];

  for (int l = 0; l < NLEV; ++l) {
    int koff = d_koff[l], k = d_k[l];
    bool in = tid < k;
    float s = in ? sprime[(size_t)b * KTOT + koff + tid] : -1.0f;
    bool valid = in && (s >= 0.0f);
    unsigned long long mb = __ballot(valid);
    if (lane == 0) s_wcnt[wv] = __popcll(mb);
    __syncthreads();
    int pre = 0;
    for (int w = 0; w < wv; ++w) pre += s_wcnt[w];
    int vrank = pre + __popcll(mb & ((1ull << lane) - 1ull));
    if (valid) { s_sc[koff + vrank] = s; s_src[koff + vrank] = tid; }
    if (in && !valid) s_iv[koff + (tid - vrank)] = tid;
    if (tid == 0) {
      int t = 0;
      for (int w = 0; w < 16; ++w) t += s_wcnt[w];
      s_V[l] = t;
    }
    __syncthreads();
  }
  int V[NLEV], VT = 0;
  for (int l = 0; l < NLEV; ++l) { V[l] = s_V[l]; VT += V[l]; }
  int IOff[NLEV];
  { int run = VT; for (int l = 0; l < NLEV; ++l) { IOff[l] = run; run += d_k[l] - V[l]; } }
  if (tid < NLEV) g_V[b * NLEV + tid] = V[tid];
  float mv1 = maxv[b] + 1.0f;

  for (int e = tid; e < KTOT; e += 1024) {
    int le = (e < 1000) ? 0 : (e < 2000) ? 1 : (e < 3000) ? 2 : (e < 4000) ? 3 : 4;
    int koff = d_koff[le];
    int i = e - koff;          // level-local compacted index (valids first)
    int rank, srcpos;
    float sval;
    if (i < V[le]) {
      float s = s_sc[e];
      rank = i;
      for (int l2 = 0; l2 < NLEV; ++l2) {
        if (l2 == le) continue;
        const float* A = s_sc + d_koff[l2];
        rank += (l2 < le) ? cnt_ge(A, V[l2], s) : cnt_gt(A, V[l2], s);
      }
      srcpos = koff + s_src[e];
      sval = s;
    } else {
      int j = i - V[le];
      rank = IOff[le] + j;
      srcpos = koff + s_iv[koff + j];
      sval = -1.0f;
    }
    score_sorted[(size_t)b * KTOT + rank] = sval;
    lvl_sorted[b * KTOT + rank] = le;
    const float* bp = boxes + ((size_t)(b * KTOT + srcpos)) * 4;
    float x1 = bp[0], y1 = bp[1], x2 = bp[2], y2 = bp[3];
    float* op = boxes_sorted + ((size_t)(b * KTOT + rank)) * 4;
    op[0] = x1; op[1] = y1; op[2] = x2; op[3] = y2;
    float off = (float)le * mv1;
    int blx = b * NLEV + le;
    lvlbox[blx * 1024 + i] = make_float4(x1 + off, y1 + off, x2 + off, y2 + off);
    lvlrank[blx * 1024 + i] = rank;
  }
}

// ---------------------------------------------------------------------------
// K4: fused blocked NMS — thread tid owns level rank tid; wave c == chunk c.
// Input is pre-compacted by k_merge. Per chunk: A) own-wave sup ballot +
// distributed diagonal bits; B) 64-step serial register scan (wave 0);
// C) later waves test own position vs the chunk's kept boxes (uniform
// broadcast LDS reads, no early break -> pipelineable). Exact div-free IoU.
// ---------------------------------------------------------------------------
__global__ __launch_bounds__(1024) void k_nms(const float4* __restrict__ lvlbox,
                                              const int* __restrict__ lvlrank,
                                              const int* __restrict__ g_V,
                                              int* __restrict__ keep_g) {
  int bl = blockIdx.x;
  int b = bl / NLEV, l = bl % NLEV;
  int tid = threadIdx.x, lane = tid & 63, wv = tid >> 6;
  const int m = d_k[l];
  __shared__ float4 lbox[1024];
  __shared__ unsigned long long s_D[72];  // 64 + 8 pad (phase-B prefetch)
  __shared__ unsigned long long s_w0, s_dw;
  int V = g_V[bl];
  bool active = (tid < m);
  float4 mybox = make_float4(0.f, 0.f, 0.f, 0.f);
  float myar = 0.f;
  bool sup = true;
  if (active) {
    float4 t = lvlbox[bl * 1024 + tid];
    lbox[tid] = t;
    mybox = t;
    myar = (t.z - t.x) * (t.w - t.y);
    sup = (tid >= V);
  }
  if (tid < 72) s_D[tid] = 0ull;
  __syncthreads();

  const int nch = (m + 63) / 64;
  for (int c = 0; c < nch; ++c) {
    int base = c * 64;
    // ---- phase A: own-wave sup ballot + distributed diagonal bits ----
    if (wv == c) {
      unsigned long long mbv = __ballot(sup);
      if (lane == 0) s_w0 = mbv;
    }
    {
      int gi = base + lane;
      if (gi < m) {
        float4 bb = lbox[gi];
        float ba = (bb.z - bb.x) * (bb.w - bb.y);
        unsigned long long bits = 0ull;
        for (int jp = lane + 1 + wv; jp < 64; jp += 16) {
          int gj = base + jp;
          if (gj < m) {
            float4 cb = lbox[gj];
            float ca = (cb.z - cb.x) * (cb.w - cb.y);
            float xx1 = fmaxf(bb.x, cb.x), yy1 = fmaxf(bb.y, cb.y);
            float xx2 = fminf(bb.z, cb.z), yy2 = fminf(bb.w, cb.w);
            float wd = fmaxf(xx2 - xx1, 0.0f), ht = fmaxf(yy2 - yy1, 0.0f);
            float inter = wd * ht;
            float denom = fmaxf(ba + ca - inter, 1e-9f);
            if ((double)inter >= TM_IOU * (double)denom) bits |= (1ull << jp);
          }
        }
        if (bits) {
          unsigned int lo = (unsigned int)bits, hi = (unsigned int)(bits >> 32);
          if (lo) atomicOr((unsigned int*)&s_D[lane], lo);
          if (hi) atomicOr(((unsigned int*)&s_D[lane]) + 1, hi);
        }
      }
    }
    __syncthreads();
    // ---- phase B: serial in-chunk scan (wave 0, redundant lanes, prefetch) ----
    if (tid < 64) {
      unsigned long long dw = s_w0;
      unsigned long long pb[8];
#pragma unroll
      for (int u = 0; u < 8; ++u) pb[u] = s_D[u];
#pragma unroll
      for (int g = 0; g < 8; ++g) {
#pragma unroll
        for (int u = 0; u < 8; ++u) {
          int j = g * 8 + u;
          if (!((dw >> j) & 1ull)) dw |= pb[u];
          pb[u] = s_D[j + 8];  // decision-independent prefetch (padded)
        }
      }
      if (tid == 0) s_dw = dw;
    }
    __syncthreads();
    // ---- phase C: resolve own wave; later waves test vs kept set ----
    if (wv == c) {
      if (active) sup = ((s_dw >> lane) & 1ull) != 0ull;
    } else if (wv > c && active) {
      unsigned long long K = ~s_dw;
      bool any = (__ballot(!sup) != 0ull);
      if (any) {
        unsigned long long W = K;
        while (W) {
          int j = __builtin_ctzll(W);
          W &= W - 1;
          float4 bb = lbox[base + j];                  // uniform broadcast load
          float ba = (bb.z - bb.x) * (bb.w - bb.y);
          float xx1 = fmaxf(bb.x, mybox.x), yy1 = fmaxf(bb.y, mybox.y);
          float xx2 = fminf(bb.z, mybox.z), yy2 = fminf(bb.w, mybox.w);
          float wd = fmaxf(xx2 - xx1, 0.0f), ht = fmaxf(yy2 - yy1, 0.0f);
          float inter = wd * ht;
          float denom = fmaxf(ba + myar - inter, 1e-9f);
          sup = sup || ((double)inter >= TM_IOU * (double)denom);
        }
      }
    }
    if (tid < 64) s_D[tid] = 0ull;  // clear for next chunk (phase C ignores s_D)
    __syncthreads();
  }
  // ---- emit keep flags in global sorted positions ----
  if (active) keep_g[b * KTOT + lvlrank[bl * 1024 + tid]] = sup ? 0 : 1;
}

// ---------------------------------------------------------------------------
// K5: emit first 1000 kept (in global sorted order) per image; zero-pad rest
// ---------------------------------------------------------------------------
__global__ __launch_bounds__(256) void k_out(const float* __restrict__ boxes_sorted,
                                             const float* __restrict__ score_sorted,
                                             const int* __restrict__ keep_g,
                                             float* __restrict__ out) {
  int b = blockIdx.x, tid = threadIdx.x;
  __shared__ int s_wcnt[4], s_base;
  for (int i = tid; i < 5000; i += 256) out[(size_t)b * 5000 + i] = 0.0f;
  if (tid == 0) s_base = 0;
  __syncthreads();
  for (int chunk = 0; chunk < KTOT; chunk += 256) {
    int j = chunk + tid;
    bool match = (j < KTOT) && (keep_g[b * KTOT + j] != 0);
    unsigned long long mb = __ballot(match);
    if ((tid & 63) == 0) s_wcnt[tid >> 6] = __popcll(mb);
    __syncthreads();
    int rank = s_base + __popcll(mb & ((1ull << (tid & 63)) - 1ull));
    for (int w = 0; w < (tid >> 6); ++w) rank += s_wcnt[w];
    if (match && rank < 1000) {
      const float* bp = boxes_sorted + ((size_t)(b * KTOT + j)) * 4;
      float* op = out + ((size_t)(b * 1000 + rank)) * 5;
      op[0] = bp[0]; op[1] = bp[1]; op[2] = bp[2]; op[3] = bp[3];
      op[4] = score_sorted[b * KTOT + j];
    }
    __syncthreads();
    if (tid == 0) s_base += s_wcnt[0] + s_wcnt[1] + s_wcnt[2] + s_wcnt[3];
    __syncthreads();
  }
}

extern "C" void kernel_launch(void* const* d_in, const int* in_sizes, int n_in,
                              void* d_out, int out_size, void* d_ws, size_t ws_size,
                              hipStream_t stream) {
  const float* obj     = (const float*)d_in[0];
  const float* deltas  = (const float*)d_in[1];
  const float* anchors = (const float*)d_in[2];
  float* out = (float*)d_out;

  // workspace layout (~2.7 MB; all block sizes are multiples of 16 B)
  int*   sel_idx      = (int*)d_ws;                          // [8*4576]
  float* boxes        = (float*)(sel_idx + BATCH * KTOT);    // [8*4576*4]
  float* sprime       = boxes + (size_t)BATCH * KTOT * 4;    // [8*4576]
  float* maxv         = sprime + BATCH * KTOT;               // [8] (pad to 16B ok: next off 16B-mult anyway)
  float* score_sorted = maxv + BATCH;                        // [8*4576]
  float* boxes_sorted = score_sorted + BATCH * KTOT;         // [8*4576*4]
  int*   lvl_sorted   = (int*)(boxes_sorted + (size_t)BATCH * KTOT * 4);  // [8*4576]
  int*   keep_g       = lvl_sorted + BATCH * KTOT;           // [8*4576]
  float4* lvlbox      = (float4*)(keep_g + BATCH * KTOT);    // [40*1024] float4
  int*   lvlrank      = (int*)(lvlbox + BATCH * NLEV * 1024);// [40*1024]
  int*   g_V          = lvlrank + BATCH * NLEV * 1024;       // [40]

  hipLaunchKernelGGL(k_topk, dim3(BATCH * NLEV), dim3(1024), 0, stream, obj, sel_idx, maxv);
  hipLaunchKernelGGL(k_decode, dim3((BATCH * KTOT + 255) / 256), dim3(256), 0, stream,
                     obj, deltas, anchors, sel_idx, boxes, sprime, maxv);
  hipLaunchKernelGGL(k_merge, dim3(BATCH), dim3(1024), 0, stream,
                     sprime, boxes, maxv, score_sorted, boxes_sorted, lvl_sorted,
                     lvlbox, lvlrank, g_V);
  hipLaunchKernelGGL(k_nms, dim3(BATCH * NLEV), dim3(1024), 0, stream,
                     lvlbox, lvlrank, g_V, keep_g);
  hipLaunchKernelGGL(k_out, dim3(BATCH), dim3(256), 0, stream,
                     boxes_sorted, score_sorted, keep_g, out);
}

// Round 7
// 248.719 us; speedup vs baseline: 5.9630x; 1.4519x over previous
//
#include <hip/hip_runtime.h>
#include <math.h>

#pragma clang fp contract(off)

#define A_TOTAL 196416
#define BATCH 8
#define KTOT 4576
#define NLEV 5
#define TB_CAP 2048
#define MSPLIT 16

static __device__ const int d_aoff[NLEV] = {0, 147456, 184320, 193536, 195840};
static __device__ const int d_n[NLEV]    = {147456, 36864, 9216, 2304, 576};
static __device__ const int d_k[NLEV]    = {1000, 1000, 1000, 1000, 576};
static __device__ const int d_koff[NLEV] = {0, 1000, 2000, 3000, 4000};

// Exact-equivalence constant for "RN(inter/denom) > 0.7f":
//   RN(q) > 0.7f  <=>  q >= midpoint(0.7f, nextafter(0.7f))  <=>
//   (double)inter >= TM_IOU * (double)denom  exactly (<=49 sig bits).
#define TM_IOU (0.699999988079071044921875 + 0x1p-25)

// monotone map: f32 -> u32 preserving order (no NaNs in this data)
__device__ inline unsigned int mono(float f) {
  unsigned int u = __float_as_uint(f);
  return (u & 0x80000000u) ? ~u : (u | 0x80000000u);
}

// in-LDS bitonic ascending sort; all threads of the block must call
template <typename T>
__device__ inline void bitonic_sort(T* arr, int N, int tid, int nth) {
  for (int size = 2; size <= N; size <<= 1) {
    for (int stride = size >> 1; stride > 0; stride >>= 1) {
      __syncthreads();
      for (int e = tid; e < N; e += nth) {
        int partner = e ^ stride;
        if (partner > e) {
          T a = arr[e], b2 = arr[partner];
          bool up = ((e & size) == 0);
          if (up ? (a > b2) : (a < b2)) { arr[e] = b2; arr[partner] = a; }
        }
      }
    }
  }
  __syncthreads();
}

// binary searches on a descending-sorted array
__device__ inline int cnt_gt(const float* A, int n, float s) {  // #{A[i] > s}
  int lo = 0, hi = n;
  while (lo < hi) { int mid = (lo + hi) >> 1; if (A[mid] > s) lo = mid + 1; else hi = mid; }
  return lo;
}
__device__ inline int cnt_ge(const float* A, int n, float s) {  // #{A[i] >= s}
  int lo = 0, hi = n;
  while (lo < hi) { int mid = (lo + hi) >> 1; if (A[mid] >= s) lo = mid + 1; else hi = mid; }
  return lo;
}

// ---------------------------------------------------------------------------
// K1: per (batch, level) exact top-k (lax.top_k semantics: value desc, idx asc)
// ---------------------------------------------------------------------------
__global__ __launch_bounds__(1024) void k_topk(const float* __restrict__ obj,
                                               int* __restrict__ sel_idx,
                                               float* __restrict__ maxv) {
  int bx = blockIdx.x;
  int b = bx / NLEV, l = bx % NLEV;
  int tid = threadIdx.x;
  if (tid == 0 && bx < BATCH) maxv[bx] = 0.0f;  // init for K2's atomicMax (coords >= 0)
  const int aoff = d_aoff[l], n = d_n[l], k = d_k[l], koff = d_koff[l];
  const float4* ob4 = (const float4*)(obj + (size_t)b * A_TOTAL + aoff);
  const int n4 = n >> 2;  // all level sizes divisible by 4

  __shared__ int hist[4096];                    // 16 KB
  __shared__ unsigned long long buf[TB_CAP];    // 16 KB
  __shared__ int s_grp[256];
  __shared__ int s_cnt;
  __shared__ int s_P12, s_ngt, s_cnt12;
  __shared__ unsigned int s_T20;

  for (int i = tid; i < 4096; i += 1024) hist[i] = 0;
  if (tid == 0) s_cnt = 0;
  __syncthreads();

  for (int i = tid; i < n4; i += 1024) {
    float4 v = ob4[i];
    atomicAdd(&hist[mono(v.x) >> 20], 1);
    atomicAdd(&hist[mono(v.y) >> 20], 1);
    atomicAdd(&hist[mono(v.z) >> 20], 1);
    atomicAdd(&hist[mono(v.w) >> 20], 1);
  }
  __syncthreads();
  if (tid < 256) {
    int s = 0;
    for (int j = 0; j < 16; ++j) s += hist[tid * 16 + j];
    s_grp[tid] = s;
  }
  __syncthreads();
  if (tid == 0) {
    int cum = 0, g, d;
    for (g = 255; g >= 0; --g) {
      if (cum + s_grp[g] >= k) break;
      cum += s_grp[g];
    }
    for (d = 15; d >= 0; --d) {
      int c = hist[g * 16 + d];
      if (cum + c >= k) break;
      cum += c;
    }
    int P12 = g * 16 + d;
    s_P12 = P12;
    s_ngt = cum;                 // count(prefix > P12)
    s_cnt12 = cum + hist[P12];   // count(prefix >= P12) — exact candidate count
    s_T20 = ((unsigned int)P12) << 8;
  }
  __syncthreads();

  if (s_cnt12 > TB_CAP) {
    // refine threshold by 8 more bits (extra scan; not hit on this data)
    unsigned int P12 = (unsigned int)s_P12;
    for (int i = tid; i < 256; i += 1024) hist[i] = 0;
    __syncthreads();
    for (int i = tid; i < n4; i += 1024) {
      float4 v = ob4[i];
      unsigned int a0 = mono(v.x), a1 = mono(v.y), a2 = mono(v.z), a3 = mono(v.w);
      if ((a0 >> 20) == P12) atomicAdd(&hist[(a0 >> 12) & 255], 1);
      if ((a1 >> 20) == P12) atomicAdd(&hist[(a1 >> 12) & 255], 1);
      if ((a2 >> 20) == P12) atomicAdd(&hist[(a2 >> 12) & 255], 1);
      if ((a3 >> 20) == P12) atomicAdd(&hist[(a3 >> 12) & 255], 1);
    }
    __syncthreads();
    if (tid == 0) {
      int cum = s_ngt, d;
      for (d = 255; d >= 0; --d) {
        int c = hist[d];
        if (cum + c >= k) break;
        cum += c;
      }
      s_T20 = (((unsigned int)s_P12) << 8) | (unsigned int)d;
    }
    __syncthreads();
  }
  unsigned int T20 = s_T20;

  for (int i = tid; i < n4; i += 1024) {
    float4 v = ob4[i];
    unsigned int kk[4] = {mono(v.x), mono(v.y), mono(v.z), mono(v.w)};
#pragma unroll
    for (int c = 0; c < 4; ++c) {
      if ((kk[c] >> 12) >= T20) {
        int slot = atomicAdd(&s_cnt, 1);
        if (slot < TB_CAP)
          buf[slot] = ((unsigned long long)kk[c] << 32) |
                      (unsigned int)(~(unsigned int)(4 * i + c));
      }
    }
  }
  __syncthreads();
  int cnt = min(s_cnt, TB_CAP);
  int N = (cnt <= 1024) ? 1024 : 2048;  // k <= 1000 < 1024 always
  for (int i = tid; i < N; i += 1024) if (i >= cnt) buf[i] = 0ull;
  __syncthreads();
  bitonic_sort(buf, N, tid, 1024);  // ascending (key asc, then idx desc)
  if (tid < k) {
    unsigned long long e = buf[N - 1 - tid];  // rank tid: key desc, idx asc on ties
    unsigned int idx = ~(unsigned int)(e & 0xFFFFFFFFull);
    sel_idx[b * KTOT + koff + tid] = aoff + (int)idx;
  }
}

// ---------------------------------------------------------------------------
// K2: decode + clip + sigmoid + validity for the selected 8x4576 anchors.
// ---------------------------------------------------------------------------
__global__ __launch_bounds__(256) void k_decode(const float* __restrict__ obj,
                                                const float* __restrict__ deltas,
                                                const float* __restrict__ anchors,
                                                const int* __restrict__ sel_idx,
                                                float* __restrict__ boxes,
                                                float* __restrict__ sprime,
                                                float* __restrict__ maxv) {
  __shared__ unsigned int s_max[2];
  int g = blockIdx.x * 256 + threadIdx.x;
  int b0 = (blockIdx.x * 256) / KTOT;  // first batch this block touches
  if (threadIdx.x < 2) s_max[threadIdx.x] = 0u;
  __syncthreads();
  if (g < BATCH * KTOT) {
    int b = g / KTOT;
    int gidx = sel_idx[g];
    float o = obj[(size_t)b * A_TOTAL + gidx];
    const float* dl = deltas + ((size_t)b * A_TOTAL + gidx) * 4;
    const float* an = anchors + (size_t)gidx * 4;
    float a0 = an[0], a1 = an[1], a2 = an[2], a3 = an[3];
    float wa = a2 - a0, ha = a3 - a1;
    float cxa = a0 + 0.5f * wa, cya = a1 + 0.5f * ha;
    float dx = dl[0], dy = dl[1];
    const float CLIPV = 4.135166556742356f;  // log(1000/16)
    float dw = fminf(dl[2], CLIPV), dh = fminf(dl[3], CLIPV);
    float pcx = dx * wa + cxa;               // contract(off): separate mul+add like numpy
    float pcy = dy * ha + cya;
    float pw = (float)exp((double)dw) * wa;  // correctly-rounded f32 exp
    float ph = (float)exp((double)dh) * ha;
    float x1 = pcx - 0.5f * pw, y1 = pcy - 0.5f * ph;
    float x2 = pcx + 0.5f * pw, y2 = pcy + 0.5f * ph;
    x1 = fminf(fmaxf(x1, 0.0f), 1024.0f);
    x2 = fminf(fmaxf(x2, 0.0f), 1024.0f);
    y1 = fminf(fmaxf(y1, 0.0f), 768.0f);
    y2 = fminf(fmaxf(y2, 0.0f), 768.0f);
    boxes[(size_t)g * 4 + 0] = x1;
    boxes[(size_t)g * 4 + 1] = y1;
    boxes[(size_t)g * 4 + 2] = x2;
    boxes[(size_t)g * 4 + 3] = y2;
    float s = (float)(1.0 / (1.0 + exp(-(double)o)));  // correctly-rounded sigmoid
    bool valid = ((x2 - x1) >= 1.0f) && ((y2 - y1) >= 1.0f) && (s >= 0.0f);
    sprime[g] = valid ? s : -1.0f;
    float mx = fmaxf(fmaxf(x1, y1), fmaxf(x2, y2));
    atomicMax(&s_max[b - b0], __float_as_uint(mx));  // coords >= 0 -> uint order ok
  }
  __syncthreads();
  if (threadIdx.x < 2 && b0 + (int)threadIdx.x < BATCH)
    atomicMax((unsigned int*)&maxv[b0 + threadIdx.x], s_max[threadIdx.x]);
}

// ---------------------------------------------------------------------------
// K3: merge-rank stable sort + NMS pre-compaction (see round-5 notes).
// ---------------------------------------------------------------------------
__global__ __launch_bounds__(1024) void k_merge(const float* __restrict__ sprime,
                                                const float* __restrict__ boxes,
                                                const float* __restrict__ maxv,
                                                float* __restrict__ score_sorted,
                                                float* __restrict__ boxes_sorted,
                                                int* __restrict__ lvl_sorted,
                                                float4* __restrict__ lvlbox,
                                                int* __restrict__ lvlrank,
                                                int* __restrict__ g_V) {
  int b = blockIdx.x, tid = threadIdx.x, lane = tid & 63, wv = tid >> 6;
  __shared__ float s_sc[KTOT];   // compacted valid scores, at level offsets
  __shared__ int s_src[KTOT];    // valid: level-local original index
  __shared__ int s_iv[KTOT];     // invalid: level-local original index
  __shared__ int s_V[NLEV];
  __shared__ int s_wcnt[16];

  for (int l = 0; l < NLEV; ++l) {
    int koff = d_koff[l], k = d_k[l];
    bool in = tid < k;
    float s = in ? sprime[(size_t)b * KTOT + koff + tid] : -1.0f;
    bool valid = in && (s >= 0.0f);
    unsigned long long mb = __ballot(valid);
    if (lane == 0) s_wcnt[wv] = __popcll(mb);
    __syncthreads();
    int pre = 0;
    for (int w = 0; w < wv; ++w) pre += s_wcnt[w];
    int vrank = pre + __popcll(mb & ((1ull << lane) - 1ull));
    if (valid) { s_sc[koff + vrank] = s; s_src[koff + vrank] = tid; }
    if (in && !valid) s_iv[koff + (tid - vrank)] = tid;
    if (tid == 0) {
      int t = 0;
      for (int w = 0; w < 16; ++w) t += s_wcnt[w];
      s_V[l] = t;
    }
    __syncthreads();
  }
  int V[NLEV], VT = 0;
  for (int l = 0; l < NLEV; ++l) { V[l] = s_V[l]; VT += V[l]; }
  int IOff[NLEV];
  { int run = VT; for (int l = 0; l < NLEV; ++l) { IOff[l] = run; run += d_k[l] - V[l]; } }
  if (tid < NLEV) g_V[b * NLEV + tid] = V[tid];
  float mv1 = maxv[b] + 1.0f;

  for (int e = tid; e < KTOT; e += 1024) {
    int le = (e < 1000) ? 0 : (e < 2000) ? 1 : (e < 3000) ? 2 : (e < 4000) ? 3 : 4;
    int koff = d_koff[le];
    int i = e - koff;          // level-local compacted index (valids first)
    int rank, srcpos;
    float sval;
    if (i < V[le]) {
      float s = s_sc[e];
      rank = i;
      for (int l2 = 0; l2 < NLEV; ++l2) {
        if (l2 == le) continue;
        const float* A = s_sc + d_koff[l2];
        rank += (l2 < le) ? cnt_ge(A, V[l2], s) : cnt_gt(A, V[l2], s);
      }
      srcpos = koff + s_src[e];
      sval = s;
    } else {
      int j = i - V[le];
      rank = IOff[le] + j;
      srcpos = koff + s_iv[koff + j];
      sval = -1.0f;
    }
    score_sorted[(size_t)b * KTOT + rank] = sval;
    lvl_sorted[b * KTOT + rank] = le;
    const float* bp = boxes + ((size_t)(b * KTOT + srcpos)) * 4;
    float x1 = bp[0], y1 = bp[1], x2 = bp[2], y2 = bp[3];
    float* op = boxes_sorted + ((size_t)(b * KTOT + rank)) * 4;
    op[0] = x1; op[1] = y1; op[2] = x2; op[3] = y2;
    float off = (float)le * mv1;
    int blx = b * NLEV + le;
    lvlbox[blx * 1024 + i] = make_float4(x1 + off, y1 + off, x2 + off, y2 + off);
    lvlrank[blx * 1024 + i] = rank;
  }
}

// ---------------------------------------------------------------------------
// K4a: suppression bitmask matrix, word-major layout masks[bl][word][row].
// 640 blocks (40 x MSPLIT); wave w of each block computes word w for its 64
// rows vs LDS-resident boxes (uniform-j broadcast reads; coalesced writes).
// Spreads the O(m^2/2) pairwise IoU work across all CUs.
// ---------------------------------------------------------------------------
__global__ __launch_bounds__(1024) void k_mask(const float4* __restrict__ lvlbox,
                                               unsigned long long* __restrict__ masks) {
  int blk = blockIdx.x;
  int bl = blk / MSPLIT, part = blk % MSPLIT;
  int l = bl % NLEV;
  const int m = d_k[l];
  int row0 = part * 64;
  if (row0 >= m) return;                      // uniform early-exit (before barrier)
  int tid = threadIdx.x, lane = tid & 63, w = tid >> 6;
  __shared__ float4 lbox[1024];
  for (int i = tid; i < m; i += 1024) lbox[i] = lvlbox[bl * 1024 + i];
  __syncthreads();
  int i = row0 + lane;                        // my row
  if (i >= m) return;                         // per-lane exit after last barrier
  float4 bb = lbox[i];
  float ba = (bb.z - bb.x) * (bb.w - bb.y);
  unsigned long long bits = 0ull;
  int jbase = w * 64;
  if (jbase + 63 > i && jbase < m) {          // word contains some j>i, j<m
    int jhi = min(64, m - jbase);
    for (int jo = 0; jo < jhi; ++jo) {        // j uniform across the wave
      int j = jbase + jo;
      float4 cb = lbox[j];
      float ca = (cb.z - cb.x) * (cb.w - cb.y);
      float xx1 = fmaxf(bb.x, cb.x), yy1 = fmaxf(bb.y, cb.y);
      float xx2 = fminf(bb.z, cb.z), yy2 = fminf(bb.w, cb.w);
      float wd = fmaxf(xx2 - xx1, 0.0f), ht = fmaxf(yy2 - yy1, 0.0f);
      float inter = wd * ht;
      float denom = fmaxf(ba + ca - inter, 1e-9f);
      if ((j > i) && ((double)inter >= TM_IOU * (double)denom)) bits |= (1ull << jo);
    }
  }
  masks[((size_t)bl * 16 + w) * 1024 + i] = bits;  // coalesced across lanes
}

// ---------------------------------------------------------------------------
// K4b: serial bitmask scan, one block per (b,l). Wave w owns suppression word
// w: register accumulator acc = OR of mask-word-w over kept rows so far.
// Per chunk c: all waves pre-issue their (kept-independent) coalesced load;
// wave c butterfly-ORs acc (6 shfl_xor), runs the 64-step diagonal scan
// (s_D double-buffered, prefetched by wave c+1), publishes s_dw; other waves
// mask with kept bits and fold into acc. No LDS atomics on the critical path.
// ---------------------------------------------------------------------------
__global__ __launch_bounds__(1024) void k_scan(const unsigned long long* __restrict__ masks,
                                               const int* __restrict__ lvlrank,
                                               const int* __restrict__ g_V,
                                               int* __restrict__ keep_g) {
  int bl = blockIdx.x;
  int b = bl / NLEV, l = bl % NLEV;
  int tid = threadIdx.x, lane = tid & 63, w = tid >> 6;
  const int m = d_k[l];
  const int nch = (m + 63) / 64;
  const unsigned long long* M = masks + (size_t)bl * 16 * 1024;
  __shared__ unsigned long long s_remv[16];
  __shared__ unsigned long long s_D[2][72];   // 64 + 8 pad (scan prefetch)
  __shared__ unsigned long long s_dw;
  int V = g_V[bl];
  // init word: suppress local rank >= V (covers rank >= m too, V <= m)
  int base_w = w * 64;
  unsigned long long init_w;
  if (V <= base_w) init_w = ~0ull;
  else if (V >= base_w + 64) init_w = 0ull;
  else init_w = (~0ull) << (V - base_w);
  if (w == 0) s_D[0][lane] = (lane < m) ? M[lane] : 0ull;  // word 0, rows 0..63
  if (tid < 8) { s_D[0][64 + tid] = 0ull; s_D[1][64 + tid] = 0ull; }
  unsigned long long acc = 0ull;
  __syncthreads();

  for (int c = 0; c < nch; ++c) {
    // issue this chunk's mask-word load early (kept-independent)
    unsigned long long val = 0ull;
    int r = 64 * c + lane;
    if (w > c && w < nch && r < m) val = M[(size_t)w * 1024 + r];
    // scanning wave: reduce acc, then serial 64-step diagonal scan
    if (w == c) {
      unsigned long long red = acc;
#pragma unroll
      for (int s = 1; s < 64; s <<= 1) red |= __shfl_xor(red, s);
      unsigned long long dw = init_w | red;
      const unsigned long long* D = s_D[c & 1];
      unsigned long long pb[8];
#pragma unroll
      for (int u = 0; u < 8; ++u) pb[u] = D[u];
#pragma unroll
      for (int g = 0; g < 8; ++g) {
#pragma unroll
        for (int u = 0; u < 8; ++u) {
          int j = g * 8 + u;
          if (!((dw >> j) & 1ull)) dw |= pb[u];
          pb[u] = D[j + 8];  // decision-independent prefetch (padded)
        }
      }
      if (lane == 0) { s_dw = dw; s_remv[c] = dw; }
    }
    // prefetch next chunk's diagonal words (other LDS buffer, no race)
    if (w == c + 1 && w < nch) {
      int rr = 64 * (c + 1) + lane;
      s_D[(c + 1) & 1][lane] = (rr < m) ? M[(size_t)(c + 1) * 1024 + rr] : 0ull;
    }
    __syncthreads();
    // fold kept rows' words into own accumulator
    if (w > c && w < nch) {
      unsigned long long kept = ~s_dw;
      if ((kept >> lane) & 1ull) acc |= val;
    }
    __syncthreads();  // protect s_dw before next chunk overwrites it
  }
  for (int i = tid; i < m; i += 1024) {
    int keep = ((s_remv[i >> 6] >> (i & 63)) & 1ull) ? 0 : 1;
    keep_g[b * KTOT + lvlrank[bl * 1024 + i]] = keep;
  }
}

// ---------------------------------------------------------------------------
// K5: emit first 1000 kept (in global sorted order) per image; zero-pad rest
// ---------------------------------------------------------------------------
__global__ __launch_bounds__(256) void k_out(const float* __restrict__ boxes_sorted,
                                             const float* __restrict__ score_sorted,
                                             const int* __restrict__ keep_g,
                                             float* __restrict__ out) {
  int b = blockIdx.x, tid = threadIdx.x;
  __shared__ int s_wcnt[4], s_base;
  for (int i = tid; i < 5000; i += 256) out[(size_t)b * 5000 + i] = 0.0f;
  if (tid == 0) s_base = 0;
  __syncthreads();
  for (int chunk = 0; chunk < KTOT; chunk += 256) {
    int j = chunk + tid;
    bool match = (j < KTOT) && (keep_g[b * KTOT + j] != 0);
    unsigned long long mb = __ballot(match);
    if ((tid & 63) == 0) s_wcnt[tid >> 6] = __popcll(mb);
    __syncthreads();
    int rank = s_base + __popcll(mb & ((1ull << (tid & 63)) - 1ull));
    for (int w = 0; w < (tid >> 6); ++w) rank += s_wcnt[w];
    if (match && rank < 1000) {
      const float* bp = boxes_sorted + ((size_t)(b * KTOT + j)) * 4;
      float* op = out + ((size_t)(b * 1000 + rank)) * 5;
      op[0] = bp[0]; op[1] = bp[1]; op[2] = bp[2]; op[3] = bp[3];
      op[4] = score_sorted[b * KTOT + j];
    }
    __syncthreads();
    if (tid == 0) s_base += s_wcnt[0] + s_wcnt[1] + s_wcnt[2] + s_wcnt[3];
    __syncthreads();
  }
}

extern "C" void kernel_launch(void* const* d_in, const int* in_sizes, int n_in,
                              void* d_out, int out_size, void* d_ws, size_t ws_size,
                              hipStream_t stream) {
  const float* obj     = (const float*)d_in[0];
  const float* deltas  = (const float*)d_in[1];
  const float* anchors = (const float*)d_in[2];
  float* out = (float*)d_out;

  // workspace layout (~8 MB; all offsets 16 B aligned)
  int*   sel_idx      = (int*)d_ws;                          // [8*4576]
  float* boxes        = (float*)(sel_idx + BATCH * KTOT);    // [8*4576*4]
  float* sprime       = boxes + (size_t)BATCH * KTOT * 4;    // [8*4576]
  float* maxv         = sprime + BATCH * KTOT;               // [8]
  float* score_sorted = maxv + BATCH;                        // [8*4576]
  float* boxes_sorted = score_sorted + BATCH * KTOT;         // [8*4576*4]
  int*   lvl_sorted   = (int*)(boxes_sorted + (size_t)BATCH * KTOT * 4);  // [8*4576]
  int*   keep_g       = lvl_sorted + BATCH * KTOT;           // [8*4576]
  float4* lvlbox      = (float4*)(keep_g + BATCH * KTOT);    // [40*1024] float4
  int*   lvlrank      = (int*)(lvlbox + BATCH * NLEV * 1024);// [40*1024]
  int*   g_V          = lvlrank + BATCH * NLEV * 1024;       // [40] (+pad)
  unsigned long long* masks = (unsigned long long*)(((uintptr_t)(g_V + 40) + 15) & ~(uintptr_t)15);  // [40*16*1024] = 5.24 MB

  hipLaunchKernelGGL(k_topk, dim3(BATCH * NLEV), dim3(1024), 0, stream, obj, sel_idx, maxv);
  hipLaunchKernelGGL(k_decode, dim3((BATCH * KTOT + 255) / 256), dim3(256), 0, stream,
                     obj, deltas, anchors, sel_idx, boxes, sprime, maxv);
  hipLaunchKernelGGL(k_merge, dim3(BATCH), dim3(1024), 0, stream,
                     sprime, boxes, maxv, score_sorted, boxes_sorted, lvl_sorted,
                     lvlbox, lvlrank, g_V);
  hipLaunchKernelGGL(k_mask, dim3(BATCH * NLEV * MSPLIT), dim3(1024), 0, stream,
                     lvlbox, masks);
  hipLaunchKernelGGL(k_scan, dim3(BATCH * NLEV), dim3(1024), 0, stream,
                     masks, lvlrank, g_V, keep_g);
  hipLaunchKernelGGL(k_out, dim3(BATCH), dim3(256), 0, stream,
                     boxes_sorted, score_sorted, keep_g, out);
}